// Round 3
// baseline (1740.602 us; speedup 1.0000x reference)
//
#include <hip/hip_runtime.h>
#include <hip/hip_bf16.h>

typedef unsigned int u32;
typedef unsigned short u16;
typedef __attribute__((ext_vector_type(8))) __bf16 bf16x8;
typedef __attribute__((ext_vector_type(8))) unsigned short u16x8;
typedef __attribute__((ext_vector_type(4))) float f32x4;

#define SEQ 2048

__device__ __forceinline__ float b2f(u16 u) {
  union { u32 i; float f; } x; x.i = ((u32)u) << 16; return x.f;
}
__device__ __forceinline__ u16 f2b(float f) {
  u32 u = __float_as_uint(f);
  u = (u + 0x7fffu + ((u >> 16) & 1u)) >> 16;
  return (u16)u;
}
__device__ __forceinline__ void gload_lds16(const void* g, void* l) {
  __builtin_amdgcn_global_load_lds((const __attribute__((address_space(1))) u32*)g,
                                   (__attribute__((address_space(3))) u32*)l, 16, 0, 0);
}

// ---------------------------------------------------------------------------
// GEMM: C[M][N] = A[M][K](bf16) * Bt[N][K]^T (fp32 weights, cvt to bf16 in
// staging). M = 2048 (16 blocks of 128). 1-D grid, bijective chunked XCD
// swizzle, M-fast decode so 16 consecutive blocks share one B-panel.
// Pipelined min-2-phase K-loop: LDS double-buffer, prefetch issued before
// compute, B cvt+ds_write after MFMA (T14 split), ONE vmcnt(0)+barrier/step.
// EPI 0: store fp32 C0[r*N+col]
// EPI 1: QKV head-major bf16: out[(col>>6)][r][col&63], out selected by which
// EPI 2: bf16 store of gelu(acc + bias[col])
// EPI 3: atomicAdd fp32 into C0[r*N+col] (+bias on z==0) -- split-K
// ---------------------------------------------------------------------------
template <int EPI>
__global__ __launch_bounds__(256) void gemm_bt(
    const u16* __restrict__ A, const float* __restrict__ B0q,
    const float* __restrict__ B1k, const float* __restrict__ B2v,
    void* __restrict__ C0, void* __restrict__ C1, void* __restrict__ C2,
    const float* __restrict__ bias, int N, int K, int nblk)
{
  __shared__ u16 As[2][128 * 32];
  __shared__ u16 Bs[2][128 * 32];
  const int tid = threadIdx.x;
  const int lane = tid & 63;
  const int w = tid >> 6;
  const int wr = w >> 1;
  const int wc = w & 1;

  // chunked-bijective XCD swizzle (m204) + M-fast decode
  const int T = (int)gridDim.x;
  const int bid = (int)blockIdx.x;
  const int q8 = T >> 3, r8 = T & 7;
  const int xcd = bid & 7, base = bid >> 3;
  int swz = (xcd < r8 ? xcd * (q8 + 1) : r8 * (q8 + 1) + (xcd - r8) * q8) + base;
  int which = 0;
  if (EPI == 1) { which = swz / (16 * nblk); swz -= which * 16 * nblk; }
  const float* Bt = (which == 0) ? B0q : (which == 1) ? B1k : B2v;
  const int m0 = (swz & 15) * 128;
  const int n0 = (swz >> 4) * 128;

  const int kchunk = K / (int)gridDim.z;
  const int kbeg = (int)blockIdx.z * kchunk;
  const int kend = kbeg + kchunk;

  f32x4 acc[4][4] = {};

  const u16* ga0 = A + (size_t)(m0 + w * 32 + (lane >> 2)) * K + (lane & 3) * 8;
  const float* gb0 = Bt + (size_t)(n0 + (tid >> 1)) * K + (tid & 1) * 16;
  const int lauoff = w * 32 * 32;               // per-wave A LDS offset (u16)
  const int lbwoff = (tid >> 1) * 32 + (tid & 1) * 16;

  // ---- prologue: fully stage tile kbeg into buffer 0 ----
  {
    gload_lds16(ga0 + kbeg, &As[0][lauoff]);
    gload_lds16(ga0 + kbeg + 16 * K, &As[0][lauoff + 16 * 32]);
    const float4 f0 = *(const float4*)(gb0 + kbeg);
    const float4 f1 = *(const float4*)(gb0 + kbeg + 4);
    const float4 f2 = *(const float4*)(gb0 + kbeg + 8);
    const float4 f3 = *(const float4*)(gb0 + kbeg + 12);
    union { bf16x8 b; u16x8 u; } lo, hi;
    lo.b[0] = (__bf16)f0.x; lo.b[1] = (__bf16)f0.y;
    lo.b[2] = (__bf16)f0.z; lo.b[3] = (__bf16)f0.w;
    lo.b[4] = (__bf16)f1.x; lo.b[5] = (__bf16)f1.y;
    lo.b[6] = (__bf16)f1.z; lo.b[7] = (__bf16)f1.w;
    hi.b[0] = (__bf16)f2.x; hi.b[1] = (__bf16)f2.y;
    hi.b[2] = (__bf16)f2.z; hi.b[3] = (__bf16)f2.w;
    hi.b[4] = (__bf16)f3.x; hi.b[5] = (__bf16)f3.y;
    hi.b[6] = (__bf16)f3.z; hi.b[7] = (__bf16)f3.w;
    *(u16x8*)&Bs[0][lbwoff] = lo.u;
    *(u16x8*)&Bs[0][lbwoff + 8] = hi.u;
    asm volatile("s_waitcnt vmcnt(0)" ::: "memory");
    __syncthreads();
  }

  int cur = 0;
  for (int kt = kbeg; kt < kend; kt += 32) {
    const int nxt = cur ^ 1;
    const int ktn = (kt + 32 < kend) ? kt + 32 : kbeg;  // wrap: valid addr, unused data

    // issue next-tile B global loads (to regs) + A direct-to-LDS
    const float4 f0 = *(const float4*)(gb0 + ktn);
    const float4 f1 = *(const float4*)(gb0 + ktn + 4);
    const float4 f2 = *(const float4*)(gb0 + ktn + 8);
    const float4 f3 = *(const float4*)(gb0 + ktn + 12);
    gload_lds16(ga0 + ktn, &As[nxt][lauoff]);
    gload_lds16(ga0 + ktn + 16 * K, &As[nxt][lauoff + 16 * 32]);

    // compute current tile
    bf16x8 af[4], bfr[4];
#pragma unroll
    for (int m = 0; m < 4; ++m)
      af[m] = *(const bf16x8*)&As[cur][(wr * 64 + m * 16 + (lane & 15)) * 32 + (lane >> 4) * 8];
#pragma unroll
    for (int n = 0; n < 4; ++n)
      bfr[n] = *(const bf16x8*)&Bs[cur][(wc * 64 + n * 16 + (lane & 15)) * 32 + (lane >> 4) * 8];
#pragma unroll
    for (int m = 0; m < 4; ++m)
#pragma unroll
      for (int n = 0; n < 4; ++n)
        acc[m][n] = __builtin_amdgcn_mfma_f32_16x16x32_bf16(af[m], bfr[n], acc[m][n], 0, 0, 0);

    // finish next-tile B staging (cvt + LDS write) after the MFMA cluster
    {
      union { bf16x8 b; u16x8 u; } lo, hi;
      lo.b[0] = (__bf16)f0.x; lo.b[1] = (__bf16)f0.y;
      lo.b[2] = (__bf16)f0.z; lo.b[3] = (__bf16)f0.w;
      lo.b[4] = (__bf16)f1.x; lo.b[5] = (__bf16)f1.y;
      lo.b[6] = (__bf16)f1.z; lo.b[7] = (__bf16)f1.w;
      hi.b[0] = (__bf16)f2.x; hi.b[1] = (__bf16)f2.y;
      hi.b[2] = (__bf16)f2.z; hi.b[3] = (__bf16)f2.w;
      hi.b[4] = (__bf16)f3.x; hi.b[5] = (__bf16)f3.y;
      hi.b[6] = (__bf16)f3.z; hi.b[7] = (__bf16)f3.w;
      *(u16x8*)&Bs[nxt][lbwoff] = lo.u;
      *(u16x8*)&Bs[nxt][lbwoff + 8] = hi.u;
    }
    asm volatile("s_waitcnt vmcnt(0)" ::: "memory");
    __syncthreads();
    cur = nxt;
  }

#pragma unroll
  for (int m = 0; m < 4; ++m) {
    const int rowb = m0 + wr * 64 + m * 16 + ((lane >> 4) << 2);
#pragma unroll
    for (int n = 0; n < 4; ++n) {
      const int col = n0 + wc * 64 + n * 16 + (lane & 15);
#pragma unroll
      for (int j = 0; j < 4; ++j) {
        const int r = rowb + j;
        float v = acc[m][n][j];
        if (EPI == 0) {
          ((float*)C0)[(size_t)r * N + col] = v;
        } else if (EPI == 1) {
          u16* outp = (u16*)((which == 0) ? C0 : (which == 1) ? C1 : C2);
          outp[((size_t)(col >> 6) * SEQ + r) * 64 + (col & 63)] = f2b(v);
        } else if (EPI == 2) {
          float xx = v + bias[col];
          float ge = 0.5f * xx * (1.0f + erff(xx * 0.70710678118654752f));
          ((u16*)C0)[(size_t)r * N + col] = f2b(ge);
        } else {
          float xx = v;
          if (bias != nullptr && blockIdx.z == 0) xx += bias[col];
          atomicAdd(&((float*)C0)[(size_t)r * N + col], xx);
        }
      }
    }
  }
}

// ---------------------------------------------------------------------------
// LayerNorm: fp32 x[row][1024] -> bf16 out; g/b fp32
// ---------------------------------------------------------------------------
__global__ __launch_bounds__(256) void ln_kernel(const float* __restrict__ x,
    const float* __restrict__ g, const float* __restrict__ b, u16* __restrict__ out)
{
  const int row = blockIdx.x;
  const int tid = threadIdx.x;
  const float4 v = ((const float4*)(x + (size_t)row * 1024))[tid];
  float s = v.x + v.y + v.z + v.w;
  float sq = v.x * v.x + v.y * v.y + v.z * v.z + v.w * v.w;
#pragma unroll
  for (int o = 1; o < 64; o <<= 1) { s += __shfl_xor(s, o); sq += __shfl_xor(sq, o); }
  __shared__ float ss[4], ssq[4];
  if ((tid & 63) == 0) { ss[tid >> 6] = s; ssq[tid >> 6] = sq; }
  __syncthreads();
  s = ss[0] + ss[1] + ss[2] + ss[3];
  sq = ssq[0] + ssq[1] + ssq[2] + ssq[3];
  const float mean = s * (1.0f / 1024.0f);
  const float var = sq * (1.0f / 1024.0f) - mean * mean;
  const float rstd = rsqrtf(var + 1e-5f);
  const int c = tid * 4;
  u16* o4 = out + (size_t)row * 1024 + c;
  const float4 gg = ((const float4*)g)[tid];
  const float4 bb = ((const float4*)b)[tid];
  o4[0] = f2b((v.x - mean) * rstd * gg.x + bb.x);
  o4[1] = f2b((v.y - mean) * rstd * gg.y + bb.y);
  o4[2] = f2b((v.z - mean) * rstd * gg.z + bb.z);
  o4[3] = f2b((v.w - mean) * rstd * gg.w + bb.w);
}

// ---------------------------------------------------------------------------
// Embedding gather: x[s][d] = emb_fp32[ids[s]][d]
// ---------------------------------------------------------------------------
__global__ __launch_bounds__(256) void gather_kernel(const int* __restrict__ ids,
    const float* __restrict__ emb, float* __restrict__ x)
{
  const int srow = blockIdx.x;
  const int tid = threadIdx.x;
  const int id = ids[srow];
  ((float4*)(x + (size_t)srow * 1024))[tid] =
      ((const float4*)(emb + (size_t)id * 1024))[tid];
}

// ---------------------------------------------------------------------------
// Flash attention w/ ALiBi + causal. One block = (head, 128 q rows), 4 waves
// of 32 q rows each. KV tiles of 64. q/k/v are [H][S][64] bf16.
// out[s][h*64+d] bf16.  scores = qk*0.125 - slope*(kj - qi), mask kj<=qi.
// ---------------------------------------------------------------------------
__global__ __launch_bounds__(256) void attn_kernel(
    const u16* __restrict__ q, const u16* __restrict__ k, const u16* __restrict__ v,
    const float* __restrict__ slopes, u16* __restrict__ out)
{
  const int h = blockIdx.y;
  const int q0 = blockIdx.x * 128;
  const int tid = threadIdx.x;
  const int lane = tid & 63;
  const int w = tid >> 6;
  const float slope = slopes[h];

  __shared__ u16 Ks[2][64 * 32];   // [dim-half][key row][32 dims]
  __shared__ u16 Vt[64][72];       // V transposed [d][key], padded
  __shared__ u16 Pl[4][32][72];    // per-wave P, padded

  const u16* qb = q + ((size_t)h * SEQ + q0 + w * 32) * 64;
  bf16x8 qf[2][2];
#pragma unroll
  for (int m = 0; m < 2; ++m)
#pragma unroll
    for (int kk = 0; kk < 2; ++kk)
      qf[m][kk] = *(const bf16x8*)(qb + (m * 16 + (lane & 15)) * 64 + kk * 32 + (lane >> 4) * 8);

  f32x4 o_acc[2][4] = {};
  float mrun[2][4], lrun[2][4];
#pragma unroll
  for (int m = 0; m < 2; ++m)
#pragma unroll
    for (int j = 0; j < 4; ++j) { mrun[m][j] = -1e30f; lrun[m][j] = 0.0f; }

  const int ntiles = (q0 >> 6) + 2;
  const int wmaxrow = q0 + w * 32 + 31;

  const int kkp = w >> 1, halfp = w & 1;
  const u16* gk0 = k + ((size_t)h * SEQ + halfp * 32 + (lane >> 2)) * 64 + kkp * 32 + (lane & 3) * 8;
  u16* lk = &Ks[kkp][(halfp * 32) * 32];
  const u16* gv0 = v + ((size_t)h * SEQ + lane) * 64 + w * 16;

  for (int t = 0; t < ntiles; ++t) {
    const int j0 = t << 6;
    __syncthreads();
    gload_lds16(gk0 + (size_t)j0 * 64, lk);
    gload_lds16(gk0 + (size_t)(j0 + 16) * 64, lk + 16 * 32);
    {
      const u16* gvp = gv0 + (size_t)j0 * 64;
      u16x8 v0 = *(const u16x8*)gvp;
      u16x8 v1 = *(const u16x8*)(gvp + 8);
      const int d0 = w * 16;
#pragma unroll
      for (int i = 0; i < 8; ++i) Vt[d0 + i][lane] = v0[i];
#pragma unroll
      for (int i = 0; i < 8; ++i) Vt[d0 + 8 + i][lane] = v1[i];
    }
    asm volatile("s_waitcnt vmcnt(0)" ::: "memory");
    __syncthreads();

    if (wmaxrow >= j0) {
      f32x4 s[2][4] = {};
#pragma unroll
      for (int kk = 0; kk < 2; ++kk) {
        bf16x8 kf[4];
#pragma unroll
        for (int n = 0; n < 4; ++n)
          kf[n] = *(const bf16x8*)&Ks[kk][(n * 16 + (lane & 15)) * 32 + (lane >> 4) * 8];
#pragma unroll
        for (int m = 0; m < 2; ++m)
#pragma unroll
          for (int n = 0; n < 4; ++n)
            s[m][n] = __builtin_amdgcn_mfma_f32_16x16x32_bf16(qf[m][kk], kf[n], s[m][n], 0, 0, 0);
      }
      const int rq = q0 + w * 32 + ((lane >> 4) << 2);
      const int ck = j0 + (lane & 15);
#pragma unroll
      for (int m = 0; m < 2; ++m) {
#pragma unroll
        for (int j = 0; j < 4; ++j) {
          const int qi = rq + m * 16 + j;
          float mx = -1e30f;
#pragma unroll
          for (int n = 0; n < 4; ++n) {
            const int kj = ck + n * 16;
            float val = s[m][n][j] * 0.125f - slope * (float)(kj - qi);
            val = (kj <= qi) ? val : -1e30f;
            s[m][n][j] = val;
            mx = fmaxf(mx, val);
          }
#pragma unroll
          for (int o = 1; o < 16; o <<= 1) mx = fmaxf(mx, __shfl_xor(mx, o));
          const float mnew = fmaxf(mrun[m][j], mx);
          const float alpha = __expf(mrun[m][j] - mnew);
          mrun[m][j] = mnew;
          float rs = 0.0f;
          const int prow = m * 16 + ((lane >> 4) << 2) + j;
#pragma unroll
          for (int n = 0; n < 4; ++n) {
            const float p = __expf(s[m][n][j] - mnew);
            rs += p;
            Pl[w][prow][n * 16 + (lane & 15)] = f2b(p);
          }
#pragma unroll
          for (int o = 1; o < 16; o <<= 1) rs += __shfl_xor(rs, o);
          lrun[m][j] = lrun[m][j] * alpha + rs;
#pragma unroll
          for (int n = 0; n < 4; ++n) o_acc[m][n][j] *= alpha;
        }
      }
      // PV
#pragma unroll
      for (int kk = 0; kk < 2; ++kk) {
        bf16x8 pf[2], vf[4];
#pragma unroll
        for (int m = 0; m < 2; ++m)
          pf[m] = *(const bf16x8*)&Pl[w][m * 16 + (lane & 15)][kk * 32 + (lane >> 4) * 8];
#pragma unroll
        for (int n = 0; n < 4; ++n)
          vf[n] = *(const bf16x8*)&Vt[n * 16 + (lane & 15)][kk * 32 + (lane >> 4) * 8];
#pragma unroll
        for (int m = 0; m < 2; ++m)
#pragma unroll
          for (int n = 0; n < 4; ++n)
            o_acc[m][n] = __builtin_amdgcn_mfma_f32_16x16x32_bf16(pf[m], vf[n], o_acc[m][n], 0, 0, 0);
      }
    }
  }

#pragma unroll
  for (int m = 0; m < 2; ++m) {
    const int sbase = q0 + w * 32 + m * 16 + ((lane >> 4) << 2);
#pragma unroll
    for (int n = 0; n < 4; ++n) {
      const int d = h * 64 + n * 16 + (lane & 15);
#pragma unroll
      for (int j = 0; j < 4; ++j)
        out[(size_t)(sbase + j) * 1024 + d] = f2b(o_acc[m][n][j] / lrun[m][j]);
    }
  }
}

// ---------------------------------------------------------------------------
extern "C" void kernel_launch(void* const* d_in, const int* in_sizes, int n_in,
                              void* d_out, int out_size, void* d_ws, size_t ws_size,
                              hipStream_t stream)
{
  (void)in_sizes; (void)n_in; (void)out_size; (void)ws_size;
  const int* ids = (const int*)d_in[0];
  const float* emb = (const float*)d_in[1];
  const float* slopes = (const float*)d_in[2];
  const float* Wq = (const float*)d_in[3];
  const float* Wk = (const float*)d_in[4];
  const float* Wv = (const float*)d_in[5];
  const float* Wo = (const float*)d_in[6];
  const float* W1 = (const float*)d_in[7];
  const float* b1 = (const float*)d_in[8];
  const float* W2 = (const float*)d_in[9];
  const float* b2 = (const float*)d_in[10];
  const float* g1 = (const float*)d_in[11];
  const float* be1 = (const float*)d_in[12];
  const float* g2 = (const float*)d_in[13];
  const float* be2 = (const float*)d_in[14];
  const float* gf = (const float*)d_in[15];
  const float* bfin = (const float*)d_in[16];

  // scratch carved from d_out (262 MB; all fully rewritten by final GEMM):
  char* ob = (char*)d_out;
  float* x   = (float*)ob;                         // 8 MB fp32 residual
  u16* qb    = (u16*)(ob + (size_t)( 8u << 20));   // 4 MB
  u16* kb    = (u16*)(ob + (size_t)(12u << 20));   // 4 MB
  u16* vb    = (u16*)(ob + (size_t)(16u << 20));   // 4 MB
  u16* attn  = (u16*)(ob + (size_t)(20u << 20));   // 4 MB
  u16* ff    = (u16*)(ob + (size_t)(24u << 20));   // 16 MB
  u16* h     = (u16*)d_ws;                         // 4 MB (read during logits GEMM)
  float* logits = (float*)d_out;

  gather_kernel<<<2048, 256, 0, stream>>>(ids, emb, x);

  for (int l = 0; l < 4; ++l) {
    const size_t wo = (size_t)l * 1024 * 1024;
    const size_t wf = (size_t)l * 4096 * 1024;
    ln_kernel<<<2048, 256, 0, stream>>>(x, g1 + l * 1024, be1 + l * 1024, h);
    gemm_bt<1><<<dim3(384, 1, 1), 256, 0, stream>>>(h, Wq + wo, Wk + wo, Wv + wo,
        qb, kb, vb, nullptr, 1024, 1024, 8);
    attn_kernel<<<dim3(16, 16), 256, 0, stream>>>(qb, kb, vb, slopes, attn);
    gemm_bt<3><<<dim3(128, 1, 4), 256, 0, stream>>>(attn, Wo + wo, nullptr, nullptr,
        x, nullptr, nullptr, nullptr, 1024, 1024, 8);
    ln_kernel<<<2048, 256, 0, stream>>>(x, g2 + l * 1024, be2 + l * 1024, h);
    gemm_bt<2><<<dim3(512, 1, 1), 256, 0, stream>>>(h, W1 + wf, nullptr, nullptr,
        ff, nullptr, nullptr, b1 + l * 4096, 4096, 1024, 32);
    gemm_bt<3><<<dim3(128, 1, 4), 256, 0, stream>>>(ff, W2 + wf, nullptr, nullptr,
        x, nullptr, nullptr, b2 + l * 1024, 1024, 4096, 8);
  }
  ln_kernel<<<2048, 256, 0, stream>>>(x, gf, bfin, h);
  gemm_bt<0><<<dim3(4000, 1, 1), 256, 0, stream>>>(h, emb, nullptr, nullptr,
      logits, nullptr, nullptr, nullptr, 32000, 1024, 250);
}

// Round 4
// 1494.273 us; speedup vs baseline: 1.1648x; 1.1648x over previous
//
#include <hip/hip_runtime.h>
#include <hip/hip_bf16.h>

typedef unsigned int u32;
typedef unsigned short u16;
typedef __attribute__((ext_vector_type(8))) __bf16 bf16x8;
typedef __attribute__((ext_vector_type(8))) unsigned short u16x8;
typedef __attribute__((ext_vector_type(4))) float f32x4;

#define SEQ 2048

__device__ __forceinline__ float b2f(u16 u) {
  union { u32 i; float f; } x; x.i = ((u32)u) << 16; return x.f;
}
__device__ __forceinline__ u16 f2b(float f) {
  u32 u = __float_as_uint(f);
  u = (u + 0x7fffu + ((u >> 16) & 1u)) >> 16;
  return (u16)u;
}
__device__ __forceinline__ void gload_lds16(const void* g, void* l) {
  __builtin_amdgcn_global_load_lds((const __attribute__((address_space(1))) u32*)g,
                                   (__attribute__((address_space(3))) u32*)l, 16, 0, 0);
}

// ---------------------------------------------------------------------------
// fp32 -> bf16 bulk convert (RNE via (__bf16) cast), 8 elems/thread/iter
// ---------------------------------------------------------------------------
__global__ __launch_bounds__(256) void cvt_kernel(const float* __restrict__ in,
                                                  u16* __restrict__ out, int n8)
{
  for (int i = blockIdx.x * 256 + threadIdx.x; i < n8; i += gridDim.x * 256) {
    const float4 f0 = ((const float4*)in)[i * 2];
    const float4 f1 = ((const float4*)in)[i * 2 + 1];
    union { bf16x8 b; u16x8 u; } r;
    r.b[0] = (__bf16)f0.x; r.b[1] = (__bf16)f0.y;
    r.b[2] = (__bf16)f0.z; r.b[3] = (__bf16)f0.w;
    r.b[4] = (__bf16)f1.x; r.b[5] = (__bf16)f1.y;
    r.b[6] = (__bf16)f1.z; r.b[7] = (__bf16)f1.w;
    *(u16x8*)(out + (size_t)i * 8) = r.u;
  }
}

// ---------------------------------------------------------------------------
// GEMM: C[M][N] = A[M][K](bf16) * Bt[N][K]^T. M = 2048 (16 blocks of 128).
// 1-D grid, bijective chunked XCD swizzle, M-fast decode (16 consecutive
// blocks share one B-panel). R2-proven 2-barrier K-loop, single LDS buffer.
// BF16B: B is bf16, staged via global_load_lds (m97 pattern, same as A).
// !BF16B: B is fp32, reg-staged with inline cvt (fallback for logits when
//         d_ws can't hold emb_bf16).
// EPI 0: store fp32 C0[r*N+col]
// EPI 1: QKV head-major bf16: out[(col>>6)][r][col&63], out selected by which
// EPI 2: bf16 store of gelu(acc + bias[col])
// EPI 3: atomicAdd fp32 into C0[r*N+col] (+bias on z==0) -- split-K
// ---------------------------------------------------------------------------
template <int EPI, bool BF16B>
__global__ __launch_bounds__(256) void gemm_bt(
    const u16* __restrict__ A, const void* __restrict__ B0,
    const void* __restrict__ B1, const void* __restrict__ B2,
    void* __restrict__ C0, void* __restrict__ C1, void* __restrict__ C2,
    const float* __restrict__ bias, int N, int K, int nblk)
{
  __shared__ u16 As[128 * 32];
  __shared__ u16 Bs[128 * 32];
  const int tid = threadIdx.x;
  const int lane = tid & 63;
  const int w = tid >> 6;
  const int wr = w >> 1;
  const int wc = w & 1;

  // chunked-bijective XCD swizzle (m204) + M-fast decode
  const int T = (int)gridDim.x;
  const int bid = (int)blockIdx.x;
  const int q8 = T >> 3, r8 = T & 7;
  const int xcd = bid & 7, base = bid >> 3;
  int swz = (xcd < r8 ? xcd * (q8 + 1) : r8 * (q8 + 1) + (xcd - r8) * q8) + base;
  int which = 0;
  if (EPI == 1) { which = swz / (16 * nblk); swz -= which * 16 * nblk; }
  const void* Btv = (which == 0) ? B0 : (which == 1) ? B1 : B2;
  const int m0 = (swz & 15) * 128;
  const int n0 = (swz >> 4) * 128;

  const int kchunk = K / (int)gridDim.z;
  const int kbeg = (int)blockIdx.z * kchunk;
  const int kend = kbeg + kchunk;

  f32x4 acc[4][4] = {};

  const u16* ga0 = A + (size_t)(m0 + w * 32 + (lane >> 2)) * K + (lane & 3) * 8;
  u16* la = &As[(w * 32) * 32];
  // bf16-B staging (same layout as A)
  const u16* gb16 = BF16B ? (const u16*)Btv + (size_t)(n0 + w * 32 + (lane >> 2)) * K + (lane & 3) * 8
                          : nullptr;
  u16* lb = &Bs[(w * 32) * 32];
  // fp32-B staging
  const float* gb32 = BF16B ? nullptr
                            : (const float*)Btv + (size_t)(n0 + (tid >> 1)) * K + (tid & 1) * 16;
  u16* lbw = &Bs[(tid >> 1) * 32 + (tid & 1) * 16];

  for (int kt = kbeg; kt < kend; kt += 32) {
    __syncthreads();
    gload_lds16(ga0 + kt, la);
    gload_lds16(ga0 + kt + 16 * K, la + 16 * 32);
    if (BF16B) {
      gload_lds16(gb16 + kt, lb);
      gload_lds16(gb16 + kt + 16 * K, lb + 16 * 32);
    } else {
      const float4 f0 = *(const float4*)(gb32 + kt);
      const float4 f1 = *(const float4*)(gb32 + kt + 4);
      const float4 f2 = *(const float4*)(gb32 + kt + 8);
      const float4 f3 = *(const float4*)(gb32 + kt + 12);
      union { bf16x8 b; u16x8 u; } lo, hi;
      lo.b[0] = (__bf16)f0.x; lo.b[1] = (__bf16)f0.y;
      lo.b[2] = (__bf16)f0.z; lo.b[3] = (__bf16)f0.w;
      lo.b[4] = (__bf16)f1.x; lo.b[5] = (__bf16)f1.y;
      lo.b[6] = (__bf16)f1.z; lo.b[7] = (__bf16)f1.w;
      hi.b[0] = (__bf16)f2.x; hi.b[1] = (__bf16)f2.y;
      hi.b[2] = (__bf16)f2.z; hi.b[3] = (__bf16)f2.w;
      hi.b[4] = (__bf16)f3.x; hi.b[5] = (__bf16)f3.y;
      hi.b[6] = (__bf16)f3.z; hi.b[7] = (__bf16)f3.w;
      *(u16x8*)lbw = lo.u;
      *(u16x8*)(lbw + 8) = hi.u;
    }
    asm volatile("s_waitcnt vmcnt(0)" ::: "memory");
    __syncthreads();
    bf16x8 af[4], bfr[4];
#pragma unroll
    for (int m = 0; m < 4; ++m)
      af[m] = *(const bf16x8*)&As[(wr * 64 + m * 16 + (lane & 15)) * 32 + (lane >> 4) * 8];
#pragma unroll
    for (int n = 0; n < 4; ++n)
      bfr[n] = *(const bf16x8*)&Bs[(wc * 64 + n * 16 + (lane & 15)) * 32 + (lane >> 4) * 8];
#pragma unroll
    for (int m = 0; m < 4; ++m)
#pragma unroll
      for (int n = 0; n < 4; ++n)
        acc[m][n] = __builtin_amdgcn_mfma_f32_16x16x32_bf16(af[m], bfr[n], acc[m][n], 0, 0, 0);
  }

#pragma unroll
  for (int m = 0; m < 4; ++m) {
    const int rowb = m0 + wr * 64 + m * 16 + ((lane >> 4) << 2);
#pragma unroll
    for (int n = 0; n < 4; ++n) {
      const int col = n0 + wc * 64 + n * 16 + (lane & 15);
#pragma unroll
      for (int j = 0; j < 4; ++j) {
        const int r = rowb + j;
        float v = acc[m][n][j];
        if (EPI == 0) {
          ((float*)C0)[(size_t)r * N + col] = v;
        } else if (EPI == 1) {
          u16* outp = (u16*)((which == 0) ? C0 : (which == 1) ? C1 : C2);
          outp[((size_t)(col >> 6) * SEQ + r) * 64 + (col & 63)] = f2b(v);
        } else if (EPI == 2) {
          float xx = v + bias[col];
          float ge = 0.5f * xx * (1.0f + erff(xx * 0.70710678118654752f));
          ((u16*)C0)[(size_t)r * N + col] = f2b(ge);
        } else {
          float xx = v;
          if (bias != nullptr && blockIdx.z == 0) xx += bias[col];
          atomicAdd(&((float*)C0)[(size_t)r * N + col], xx);
        }
      }
    }
  }
}

// ---------------------------------------------------------------------------
// LayerNorm: fp32 x[row][1024] -> bf16 out; g/b fp32
// ---------------------------------------------------------------------------
__global__ __launch_bounds__(256) void ln_kernel(const float* __restrict__ x,
    const float* __restrict__ g, const float* __restrict__ b, u16* __restrict__ out)
{
  const int row = blockIdx.x;
  const int tid = threadIdx.x;
  const float4 v = ((const float4*)(x + (size_t)row * 1024))[tid];
  float s = v.x + v.y + v.z + v.w;
  float sq = v.x * v.x + v.y * v.y + v.z * v.z + v.w * v.w;
#pragma unroll
  for (int o = 1; o < 64; o <<= 1) { s += __shfl_xor(s, o); sq += __shfl_xor(sq, o); }
  __shared__ float ss[4], ssq[4];
  if ((tid & 63) == 0) { ss[tid >> 6] = s; ssq[tid >> 6] = sq; }
  __syncthreads();
  s = ss[0] + ss[1] + ss[2] + ss[3];
  sq = ssq[0] + ssq[1] + ssq[2] + ssq[3];
  const float mean = s * (1.0f / 1024.0f);
  const float var = sq * (1.0f / 1024.0f) - mean * mean;
  const float rstd = rsqrtf(var + 1e-5f);
  const int c = tid * 4;
  u16* o4 = out + (size_t)row * 1024 + c;
  const float4 gg = ((const float4*)g)[tid];
  const float4 bb = ((const float4*)b)[tid];
  o4[0] = f2b((v.x - mean) * rstd * gg.x + bb.x);
  o4[1] = f2b((v.y - mean) * rstd * gg.y + bb.y);
  o4[2] = f2b((v.z - mean) * rstd * gg.z + bb.z);
  o4[3] = f2b((v.w - mean) * rstd * gg.w + bb.w);
}

// ---------------------------------------------------------------------------
// Embedding gather: x[s][d] = emb_fp32[ids[s]][d]
// ---------------------------------------------------------------------------
__global__ __launch_bounds__(256) void gather_kernel(const int* __restrict__ ids,
    const float* __restrict__ emb, float* __restrict__ x)
{
  const int srow = blockIdx.x;
  const int tid = threadIdx.x;
  const int id = ids[srow];
  ((float4*)(x + (size_t)srow * 1024))[tid] =
      ((const float4*)(emb + (size_t)id * 1024))[tid];
}

// ---------------------------------------------------------------------------
// Flash attention w/ ALiBi + causal. One block = (head, 128 q rows), 4 waves
// of 32 q rows each. KV tiles of 64. q/k/v are [H][S][64] bf16.
// out[s][h*64+d] bf16.  scores = qk*0.125 - slope*(kj - qi), mask kj<=qi.
// ---------------------------------------------------------------------------
__global__ __launch_bounds__(256) void attn_kernel(
    const u16* __restrict__ q, const u16* __restrict__ k, const u16* __restrict__ v,
    const float* __restrict__ slopes, u16* __restrict__ out)
{
  const int h = blockIdx.y;
  const int q0 = blockIdx.x * 128;
  const int tid = threadIdx.x;
  const int lane = tid & 63;
  const int w = tid >> 6;
  const float slope = slopes[h];

  __shared__ u16 Ks[2][64 * 32];   // [dim-half][key row][32 dims]
  __shared__ u16 Vt[64][72];       // V transposed [d][key], padded
  __shared__ u16 Pl[4][32][72];    // per-wave P, padded

  const u16* qb = q + ((size_t)h * SEQ + q0 + w * 32) * 64;
  bf16x8 qf[2][2];
#pragma unroll
  for (int m = 0; m < 2; ++m)
#pragma unroll
    for (int kk = 0; kk < 2; ++kk)
      qf[m][kk] = *(const bf16x8*)(qb + (m * 16 + (lane & 15)) * 64 + kk * 32 + (lane >> 4) * 8);

  f32x4 o_acc[2][4] = {};
  float mrun[2][4], lrun[2][4];
#pragma unroll
  for (int m = 0; m < 2; ++m)
#pragma unroll
    for (int j = 0; j < 4; ++j) { mrun[m][j] = -1e30f; lrun[m][j] = 0.0f; }

  const int ntiles = (q0 >> 6) + 2;
  const int wmaxrow = q0 + w * 32 + 31;

  const int kkp = w >> 1, halfp = w & 1;
  const u16* gk0 = k + ((size_t)h * SEQ + halfp * 32 + (lane >> 2)) * 64 + kkp * 32 + (lane & 3) * 8;
  u16* lk = &Ks[kkp][(halfp * 32) * 32];
  const u16* gv0 = v + ((size_t)h * SEQ + lane) * 64 + w * 16;

  for (int t = 0; t < ntiles; ++t) {
    const int j0 = t << 6;
    __syncthreads();
    gload_lds16(gk0 + (size_t)j0 * 64, lk);
    gload_lds16(gk0 + (size_t)(j0 + 16) * 64, lk + 16 * 32);
    {
      const u16* gvp = gv0 + (size_t)j0 * 64;
      u16x8 v0 = *(const u16x8*)gvp;
      u16x8 v1 = *(const u16x8*)(gvp + 8);
      const int d0 = w * 16;
#pragma unroll
      for (int i = 0; i < 8; ++i) Vt[d0 + i][lane] = v0[i];
#pragma unroll
      for (int i = 0; i < 8; ++i) Vt[d0 + 8 + i][lane] = v1[i];
    }
    asm volatile("s_waitcnt vmcnt(0)" ::: "memory");
    __syncthreads();

    if (wmaxrow >= j0) {
      f32x4 s[2][4] = {};
#pragma unroll
      for (int kk = 0; kk < 2; ++kk) {
        bf16x8 kf[4];
#pragma unroll
        for (int n = 0; n < 4; ++n)
          kf[n] = *(const bf16x8*)&Ks[kk][(n * 16 + (lane & 15)) * 32 + (lane >> 4) * 8];
#pragma unroll
        for (int m = 0; m < 2; ++m)
#pragma unroll
          for (int n = 0; n < 4; ++n)
            s[m][n] = __builtin_amdgcn_mfma_f32_16x16x32_bf16(qf[m][kk], kf[n], s[m][n], 0, 0, 0);
      }
      const int rq = q0 + w * 32 + ((lane >> 4) << 2);
      const int ck = j0 + (lane & 15);
#pragma unroll
      for (int m = 0; m < 2; ++m) {
#pragma unroll
        for (int j = 0; j < 4; ++j) {
          const int qi = rq + m * 16 + j;
          float mx = -1e30f;
#pragma unroll
          for (int n = 0; n < 4; ++n) {
            const int kj = ck + n * 16;
            float val = s[m][n][j] * 0.125f - slope * (float)(kj - qi);
            val = (kj <= qi) ? val : -1e30f;
            s[m][n][j] = val;
            mx = fmaxf(mx, val);
          }
#pragma unroll
          for (int o = 1; o < 16; o <<= 1) mx = fmaxf(mx, __shfl_xor(mx, o));
          const float mnew = fmaxf(mrun[m][j], mx);
          const float alpha = __expf(mrun[m][j] - mnew);
          mrun[m][j] = mnew;
          float rs = 0.0f;
          const int prow = m * 16 + ((lane >> 4) << 2) + j;
#pragma unroll
          for (int n = 0; n < 4; ++n) {
            const float p = __expf(s[m][n][j] - mnew);
            rs += p;
            Pl[w][prow][n * 16 + (lane & 15)] = f2b(p);
          }
#pragma unroll
          for (int o = 1; o < 16; o <<= 1) rs += __shfl_xor(rs, o);
          lrun[m][j] = lrun[m][j] * alpha + rs;
#pragma unroll
          for (int n = 0; n < 4; ++n) o_acc[m][n][j] *= alpha;
        }
      }
      // PV
#pragma unroll
      for (int kk = 0; kk < 2; ++kk) {
        bf16x8 pf[2], vf[4];
#pragma unroll
        for (int m = 0; m < 2; ++m)
          pf[m] = *(const bf16x8*)&Pl[w][m * 16 + (lane & 15)][kk * 32 + (lane >> 4) * 8];
#pragma unroll
        for (int n = 0; n < 4; ++n)
          vf[n] = *(const bf16x8*)&Vt[n * 16 + (lane & 15)][kk * 32 + (lane >> 4) * 8];
#pragma unroll
        for (int m = 0; m < 2; ++m)
#pragma unroll
          for (int n = 0; n < 4; ++n)
            o_acc[m][n] = __builtin_amdgcn_mfma_f32_16x16x32_bf16(pf[m], vf[n], o_acc[m][n], 0, 0, 0);
      }
    }
  }

#pragma unroll
  for (int m = 0; m < 2; ++m) {
    const int sbase = q0 + w * 32 + m * 16 + ((lane >> 4) << 2);
#pragma unroll
    for (int n = 0; n < 4; ++n) {
      const int d = h * 64 + n * 16 + (lane & 15);
#pragma unroll
      for (int j = 0; j < 4; ++j)
        out[(size_t)(sbase + j) * 1024 + d] = f2b(o_acc[m][n][j] / lrun[m][j]);
    }
  }
}

// ---------------------------------------------------------------------------
extern "C" void kernel_launch(void* const* d_in, const int* in_sizes, int n_in,
                              void* d_out, int out_size, void* d_ws, size_t ws_size,
                              hipStream_t stream)
{
  (void)in_sizes; (void)n_in; (void)out_size;
  const int* ids = (const int*)d_in[0];
  const float* emb = (const float*)d_in[1];
  const float* slopes = (const float*)d_in[2];
  const float* Wq = (const float*)d_in[3];
  const float* Wk = (const float*)d_in[4];
  const float* Wv = (const float*)d_in[5];
  const float* Wo = (const float*)d_in[6];
  const float* W1 = (const float*)d_in[7];
  const float* b1 = (const float*)d_in[8];
  const float* W2 = (const float*)d_in[9];
  const float* b2 = (const float*)d_in[10];
  const float* g1 = (const float*)d_in[11];
  const float* be1 = (const float*)d_in[12];
  const float* g2 = (const float*)d_in[13];
  const float* be2 = (const float*)d_in[14];
  const float* gf = (const float*)d_in[15];
  const float* bfin = (const float*)d_in[16];

  // scratch carved from d_out (262 MB; all fully rewritten by final GEMM):
  char* ob = (char*)d_out;
  float* x   = (float*)ob;                         // 8 MB fp32 residual
  u16* qb    = (u16*)(ob + (size_t)( 8u << 20));   // 4 MB
  u16* kb    = (u16*)(ob + (size_t)(12u << 20));   // 4 MB
  u16* vb    = (u16*)(ob + (size_t)(16u << 20));   // 4 MB
  u16* attn  = (u16*)(ob + (size_t)(20u << 20));   // 4 MB
  u16* ff    = (u16*)(ob + (size_t)(24u << 20));   // 16 MB
  // bf16 weight cache @40 MB (valid until the logits GEMM overwrites d_out)
  u16* Wq_b  = (u16*)(ob + (size_t)( 40u << 20));  // 8 MB
  u16* Wk_b  = (u16*)(ob + (size_t)( 48u << 20));  // 8 MB
  u16* Wv_b  = (u16*)(ob + (size_t)( 56u << 20));  // 8 MB
  u16* Wo_b  = (u16*)(ob + (size_t)( 64u << 20));  // 8 MB
  u16* W1_b  = (u16*)(ob + (size_t)( 72u << 20));  // 32 MB
  u16* W2_b  = (u16*)(ob + (size_t)(104u << 20));  // 32 MB
  u16* h     = (u16*)d_ws;                         // 4 MB (read during logits GEMM)
  const size_t emb_b_need = (size_t)(4u << 20) + (size_t)32000 * 1024 * 2;
  const bool emb_fits = ws_size >= emb_b_need;
  u16* emb_b = (u16*)((char*)d_ws + (4u << 20));   // 65.5 MB bf16 emb (if fits)
  float* logits = (float*)d_out;

  // ---- weight dtype conversion (every launch; deterministic) ----
  cvt_kernel<<<2048, 256, 0, stream>>>(Wq, Wq_b, 4 * 1024 * 1024 / 8);
  cvt_kernel<<<2048, 256, 0, stream>>>(Wk, Wk_b, 4 * 1024 * 1024 / 8);
  cvt_kernel<<<2048, 256, 0, stream>>>(Wv, Wv_b, 4 * 1024 * 1024 / 8);
  cvt_kernel<<<2048, 256, 0, stream>>>(Wo, Wo_b, 4 * 1024 * 1024 / 8);
  cvt_kernel<<<4096, 256, 0, stream>>>(W1, W1_b, 16 * 1024 * 1024 / 8);
  cvt_kernel<<<4096, 256, 0, stream>>>(W2, W2_b, 16 * 1024 * 1024 / 8);
  if (emb_fits)
    cvt_kernel<<<4096, 256, 0, stream>>>(emb, emb_b, 32000 * 1024 / 8);

  gather_kernel<<<2048, 256, 0, stream>>>(ids, emb, x);

  for (int l = 0; l < 4; ++l) {
    const size_t wo = (size_t)l * 1024 * 1024;
    const size_t wf = (size_t)l * 4096 * 1024;
    ln_kernel<<<2048, 256, 0, stream>>>(x, g1 + l * 1024, be1 + l * 1024, h);
    gemm_bt<1, true><<<dim3(384, 1, 1), 256, 0, stream>>>(h, Wq_b + wo, Wk_b + wo, Wv_b + wo,
        qb, kb, vb, nullptr, 1024, 1024, 8);
    attn_kernel<<<dim3(16, 16), 256, 0, stream>>>(qb, kb, vb, slopes, attn);
    gemm_bt<3, true><<<dim3(128, 1, 4), 256, 0, stream>>>(attn, Wo_b + wo, nullptr, nullptr,
        x, nullptr, nullptr, nullptr, 1024, 1024, 8);
    ln_kernel<<<2048, 256, 0, stream>>>(x, g2 + l * 1024, be2 + l * 1024, h);
    gemm_bt<2, true><<<dim3(512, 1, 1), 256, 0, stream>>>(h, W1_b + wf, nullptr, nullptr,
        ff, nullptr, nullptr, b1 + l * 4096, 4096, 1024, 32);
    gemm_bt<3, true><<<dim3(128, 1, 4), 256, 0, stream>>>(ff, W2_b + wf, nullptr, nullptr,
        x, nullptr, nullptr, b2 + l * 1024, 1024, 4096, 8);
  }
  ln_kernel<<<2048, 256, 0, stream>>>(x, gf, bfin, h);
  if (emb_fits) {
    gemm_bt<0, true><<<dim3(4000, 1, 1), 256, 0, stream>>>(h, emb_b, nullptr, nullptr,
        logits, nullptr, nullptr, nullptr, 32000, 1024, 250);
  } else {
    gemm_bt<0, false><<<dim3(4000, 1, 1), 256, 0, stream>>>(h, emb, nullptr, nullptr,
        logits, nullptr, nullptr, nullptr, 32000, 1024, 250);
  }
}

// Round 5
// 1429.344 us; speedup vs baseline: 1.2178x; 1.0454x over previous
//
#include <hip/hip_runtime.h>
#include <hip/hip_bf16.h>

typedef unsigned int u32;
typedef unsigned short u16;
typedef __attribute__((ext_vector_type(8))) __bf16 bf16x8;
typedef __attribute__((ext_vector_type(8))) unsigned short u16x8;
typedef __attribute__((ext_vector_type(4))) float f32x4;

#define SEQ 2048

__device__ __forceinline__ float b2f(u16 u) {
  union { u32 i; float f; } x; x.i = ((u32)u) << 16; return x.f;
}
__device__ __forceinline__ u16 f2b(float f) {
  u32 u = __float_as_uint(f);
  u = (u + 0x7fffu + ((u >> 16) & 1u)) >> 16;
  return (u16)u;
}
__device__ __forceinline__ void gload_lds16(const void* g, void* l) {
  __builtin_amdgcn_global_load_lds((const __attribute__((address_space(1))) u32*)g,
                                   (__attribute__((address_space(3))) u32*)l, 16, 0, 0);
}

// ---------------------------------------------------------------------------
// Fused fp32 -> bf16 bulk convert over up to 7 tensors (one launch).
// ---------------------------------------------------------------------------
struct CvtArgs {
  const float* src[7];
  u16* dst[7];
  u32 beg[8];   // cumulative boundaries in 8-elem granules
  u32 total;
};

__global__ __launch_bounds__(256) void cvt_all(CvtArgs a)
{
  for (u32 i = blockIdx.x * 256 + threadIdx.x; i < a.total; i += gridDim.x * 256) {
    int s = 0;
#pragma unroll
    for (int k = 1; k < 7; ++k) s += (i >= a.beg[k]);
    const u32 li = i - a.beg[s];
    const float* in = a.src[s];
    const float4 f0 = ((const float4*)in)[(size_t)li * 2];
    const float4 f1 = ((const float4*)in)[(size_t)li * 2 + 1];
    union { bf16x8 b; u16x8 u; } r;
    r.b[0] = (__bf16)f0.x; r.b[1] = (__bf16)f0.y;
    r.b[2] = (__bf16)f0.z; r.b[3] = (__bf16)f0.w;
    r.b[4] = (__bf16)f1.x; r.b[5] = (__bf16)f1.y;
    r.b[6] = (__bf16)f1.z; r.b[7] = (__bf16)f1.w;
    *(u16x8*)(a.dst[s] + (size_t)li * 8) = r.u;
  }
}

// ---------------------------------------------------------------------------
// 128x128-tile GEMM (logits): C[M][N] = A[M][K](bf16) * Bt[N][K]^T.
// M = 2048 (16 blocks of 128). R2-proven 2-barrier K-loop. XCD swizzle,
// M-fast decode. BF16B: B staged via global_load_lds; else fp32 reg-cvt.
// EPI 0: store fp32 C0[r*N+col]
// ---------------------------------------------------------------------------
template <int EPI, bool BF16B>
__global__ __launch_bounds__(256) void gemm_bt(
    const u16* __restrict__ A, const void* __restrict__ B0,
    const void* __restrict__ B1, const void* __restrict__ B2,
    void* __restrict__ C0, void* __restrict__ C1, void* __restrict__ C2,
    const float* __restrict__ bias, int N, int K, int nblk)
{
  __shared__ u16 As[128 * 32];
  __shared__ u16 Bs[128 * 32];
  const int tid = threadIdx.x;
  const int lane = tid & 63;
  const int w = tid >> 6;
  const int wr = w >> 1;
  const int wc = w & 1;

  const int T = (int)gridDim.x;
  const int bid = (int)blockIdx.x;
  const int q8 = T >> 3, r8 = T & 7;
  const int xcd = bid & 7, base = bid >> 3;
  int swz = (xcd < r8 ? xcd * (q8 + 1) : r8 * (q8 + 1) + (xcd - r8) * q8) + base;
  int which = 0;
  if (EPI == 1) { which = swz / (16 * nblk); swz -= which * 16 * nblk; }
  const void* Btv = (which == 0) ? B0 : (which == 1) ? B1 : B2;
  const int m0 = (swz & 15) * 128;
  const int n0 = (swz >> 4) * 128;

  const int kchunk = K / (int)gridDim.z;
  const int kbeg = (int)blockIdx.z * kchunk;
  const int kend = kbeg + kchunk;

  f32x4 acc[4][4] = {};

  const u16* ga0 = A + (size_t)(m0 + w * 32 + (lane >> 2)) * K + (lane & 3) * 8;
  u16* la = &As[(w * 32) * 32];
  const u16* gb16 = BF16B ? (const u16*)Btv + (size_t)(n0 + w * 32 + (lane >> 2)) * K + (lane & 3) * 8
                          : nullptr;
  u16* lb = &Bs[(w * 32) * 32];
  const float* gb32 = BF16B ? nullptr
                            : (const float*)Btv + (size_t)(n0 + (tid >> 1)) * K + (tid & 1) * 16;
  u16* lbw = &Bs[(tid >> 1) * 32 + (tid & 1) * 16];

  for (int kt = kbeg; kt < kend; kt += 32) {
    __syncthreads();
    gload_lds16(ga0 + kt, la);
    gload_lds16(ga0 + kt + 16 * K, la + 16 * 32);
    if (BF16B) {
      gload_lds16(gb16 + kt, lb);
      gload_lds16(gb16 + kt + 16 * K, lb + 16 * 32);
    } else {
      const float4 f0 = *(const float4*)(gb32 + kt);
      const float4 f1 = *(const float4*)(gb32 + kt + 4);
      const float4 f2 = *(const float4*)(gb32 + kt + 8);
      const float4 f3 = *(const float4*)(gb32 + kt + 12);
      union { bf16x8 b; u16x8 u; } lo, hi;
      lo.b[0] = (__bf16)f0.x; lo.b[1] = (__bf16)f0.y;
      lo.b[2] = (__bf16)f0.z; lo.b[3] = (__bf16)f0.w;
      lo.b[4] = (__bf16)f1.x; lo.b[5] = (__bf16)f1.y;
      lo.b[6] = (__bf16)f1.z; lo.b[7] = (__bf16)f1.w;
      hi.b[0] = (__bf16)f2.x; hi.b[1] = (__bf16)f2.y;
      hi.b[2] = (__bf16)f2.z; hi.b[3] = (__bf16)f2.w;
      hi.b[4] = (__bf16)f3.x; hi.b[5] = (__bf16)f3.y;
      hi.b[6] = (__bf16)f3.z; hi.b[7] = (__bf16)f3.w;
      *(u16x8*)lbw = lo.u;
      *(u16x8*)(lbw + 8) = hi.u;
    }
    asm volatile("s_waitcnt vmcnt(0)" ::: "memory");
    __syncthreads();
    bf16x8 af[4], bfr[4];
#pragma unroll
    for (int m = 0; m < 4; ++m)
      af[m] = *(const bf16x8*)&As[(wr * 64 + m * 16 + (lane & 15)) * 32 + (lane >> 4) * 8];
#pragma unroll
    for (int n = 0; n < 4; ++n)
      bfr[n] = *(const bf16x8*)&Bs[(wc * 64 + n * 16 + (lane & 15)) * 32 + (lane >> 4) * 8];
#pragma unroll
    for (int m = 0; m < 4; ++m)
#pragma unroll
      for (int n = 0; n < 4; ++n)
        acc[m][n] = __builtin_amdgcn_mfma_f32_16x16x32_bf16(af[m], bfr[n], acc[m][n], 0, 0, 0);
  }

#pragma unroll
  for (int m = 0; m < 4; ++m) {
    const int rowb = m0 + wr * 64 + m * 16 + ((lane >> 4) << 2);
#pragma unroll
    for (int n = 0; n < 4; ++n) {
      const int col = n0 + wc * 64 + n * 16 + (lane & 15);
#pragma unroll
      for (int j = 0; j < 4; ++j) {
        const int r = rowb + j;
        float v = acc[m][n][j];
        if (EPI == 0) {
          ((float*)C0)[(size_t)r * N + col] = v;
        } else if (EPI == 1) {
          u16* outp = (u16*)((which == 0) ? C0 : (which == 1) ? C1 : C2);
          outp[((size_t)(col >> 6) * SEQ + r) * 64 + (col & 63)] = f2b(v);
        } else if (EPI == 2) {
          float xx = v + bias[col];
          float ge = 0.5f * xx * (1.0f + erff(xx * 0.70710678118654752f));
          ((u16*)C0)[(size_t)r * N + col] = f2b(ge);
        } else {
          float xx = v;
          if (bias != nullptr && blockIdx.z == 0) xx += bias[col];
          atomicAdd(&((float*)C0)[(size_t)r * N + col], xx);
        }
      }
    }
  }
}

// ---------------------------------------------------------------------------
// 64x128-tile GEMM for layer GEMMs (small N): more blocks/CU -> overlap.
// BM=64, BN=128, BK=32, 4 waves (2Mx2N), each wave 32x64, 12 KB LDS.
// M = 2048 (32 M-blocks of 64). M-fast decode. All-bf16 operands.
// EPI 1: QKV head-major bf16 (which = block group of 256)
// EPI 2: bf16 gelu(acc + bias)
// EPI 3: atomicAdd fp32 (+bias on z==0), split-K via gridDim.z
// ---------------------------------------------------------------------------
template <int EPI>
__global__ __launch_bounds__(256) void gemm64(
    const u16* __restrict__ A, const u16* __restrict__ B0,
    const u16* __restrict__ B1, const u16* __restrict__ B2,
    void* __restrict__ C0, void* __restrict__ C1, void* __restrict__ C2,
    const float* __restrict__ bias, int N, int K)
{
  __shared__ u16 As[64 * 32];
  __shared__ u16 Bs[128 * 32];
  const int tid = threadIdx.x;
  const int lane = tid & 63;
  const int w = tid >> 6;
  const int wr = w >> 1;
  const int wc = w & 1;

  const int T = (int)gridDim.x;
  const int bid = (int)blockIdx.x;
  const int q8 = T >> 3, r8 = T & 7;
  const int xcd = bid & 7, base = bid >> 3;
  int swz = (xcd < r8 ? xcd * (q8 + 1) : r8 * (q8 + 1) + (xcd - r8) * q8) + base;
  int which = 0;
  if (EPI == 1) which = swz >> 8;              // 256 blocks (32M x 8N) per matrix
  const u16* Bt = (which == 0) ? B0 : (which == 1) ? B1 : B2;
  const int m0 = (swz & 31) * 64;
  const int n0 = (EPI == 1 ? ((swz >> 5) & 7) : (swz >> 5)) * 128;

  const int kchunk = K / (int)gridDim.z;
  const int kbeg = (int)blockIdx.z * kchunk;
  const int kend = kbeg + kchunk;

  f32x4 acc[2][4] = {};

  const u16* ga0 = A + (size_t)(m0 + w * 16 + (lane >> 2)) * K + (lane & 3) * 8;
  u16* la = &As[(w * 16) * 32];
  const u16* gb0 = Bt + (size_t)(n0 + w * 32 + (lane >> 2)) * K + (lane & 3) * 8;
  u16* lb = &Bs[(w * 32) * 32];

  for (int kt = kbeg; kt < kend; kt += 32) {
    __syncthreads();
    gload_lds16(ga0 + kt, la);
    gload_lds16(gb0 + kt, lb);
    gload_lds16(gb0 + kt + 16 * K, lb + 16 * 32);
    asm volatile("s_waitcnt vmcnt(0)" ::: "memory");
    __syncthreads();
    bf16x8 af[2], bfr[4];
#pragma unroll
    for (int m = 0; m < 2; ++m)
      af[m] = *(const bf16x8*)&As[(wr * 32 + m * 16 + (lane & 15)) * 32 + (lane >> 4) * 8];
#pragma unroll
    for (int n = 0; n < 4; ++n)
      bfr[n] = *(const bf16x8*)&Bs[(wc * 64 + n * 16 + (lane & 15)) * 32 + (lane >> 4) * 8];
#pragma unroll
    for (int m = 0; m < 2; ++m)
#pragma unroll
      for (int n = 0; n < 4; ++n)
        acc[m][n] = __builtin_amdgcn_mfma_f32_16x16x32_bf16(af[m], bfr[n], acc[m][n], 0, 0, 0);
  }

#pragma unroll
  for (int m = 0; m < 2; ++m) {
    const int rowb = m0 + wr * 32 + m * 16 + ((lane >> 4) << 2);
#pragma unroll
    for (int n = 0; n < 4; ++n) {
      const int col = n0 + wc * 64 + n * 16 + (lane & 15);
#pragma unroll
      for (int j = 0; j < 4; ++j) {
        const int r = rowb + j;
        float v = acc[m][n][j];
        if (EPI == 1) {
          u16* outp = (u16*)((which == 0) ? C0 : (which == 1) ? C1 : C2);
          outp[((size_t)(col >> 6) * SEQ + r) * 64 + (col & 63)] = f2b(v);
        } else if (EPI == 2) {
          float xx = v + bias[col];
          float ge = 0.5f * xx * (1.0f + erff(xx * 0.70710678118654752f));
          ((u16*)C0)[(size_t)r * N + col] = f2b(ge);
        } else {
          float xx = v;
          if (bias != nullptr && blockIdx.z == 0) xx += bias[col];
          atomicAdd(&((float*)C0)[(size_t)r * N + col], xx);
        }
      }
    }
  }
}

// ---------------------------------------------------------------------------
// LayerNorm: fp32 x[row][1024] -> bf16 out; g/b fp32
// ---------------------------------------------------------------------------
__global__ __launch_bounds__(256) void ln_kernel(const float* __restrict__ x,
    const float* __restrict__ g, const float* __restrict__ b, u16* __restrict__ out)
{
  const int row = blockIdx.x;
  const int tid = threadIdx.x;
  const float4 v = ((const float4*)(x + (size_t)row * 1024))[tid];
  float s = v.x + v.y + v.z + v.w;
  float sq = v.x * v.x + v.y * v.y + v.z * v.z + v.w * v.w;
#pragma unroll
  for (int o = 1; o < 64; o <<= 1) { s += __shfl_xor(s, o); sq += __shfl_xor(sq, o); }
  __shared__ float ss[4], ssq[4];
  if ((tid & 63) == 0) { ss[tid >> 6] = s; ssq[tid >> 6] = sq; }
  __syncthreads();
  s = ss[0] + ss[1] + ss[2] + ss[3];
  sq = ssq[0] + ssq[1] + ssq[2] + ssq[3];
  const float mean = s * (1.0f / 1024.0f);
  const float var = sq * (1.0f / 1024.0f) - mean * mean;
  const float rstd = rsqrtf(var + 1e-5f);
  const int c = tid * 4;
  u16* o4 = out + (size_t)row * 1024 + c;
  const float4 gg = ((const float4*)g)[tid];
  const float4 bb = ((const float4*)b)[tid];
  o4[0] = f2b((v.x - mean) * rstd * gg.x + bb.x);
  o4[1] = f2b((v.y - mean) * rstd * gg.y + bb.y);
  o4[2] = f2b((v.z - mean) * rstd * gg.z + bb.z);
  o4[3] = f2b((v.w - mean) * rstd * gg.w + bb.w);
}

// ---------------------------------------------------------------------------
// Embedding gather: x[s][d] = emb_fp32[ids[s]][d]
// ---------------------------------------------------------------------------
__global__ __launch_bounds__(256) void gather_kernel(const int* __restrict__ ids,
    const float* __restrict__ emb, float* __restrict__ x)
{
  const int srow = blockIdx.x;
  const int tid = threadIdx.x;
  const int id = ids[srow];
  ((float4*)(x + (size_t)srow * 1024))[tid] =
      ((const float4*)(emb + (size_t)id * 1024))[tid];
}

// ---------------------------------------------------------------------------
// Flash attention w/ ALiBi + causal. One block = (head, 128 q rows), 4 waves
// of 32 q rows each. KV tiles of 64. q/k/v are [H][S][64] bf16.
// ---------------------------------------------------------------------------
__global__ __launch_bounds__(256) void attn_kernel(
    const u16* __restrict__ q, const u16* __restrict__ k, const u16* __restrict__ v,
    const float* __restrict__ slopes, u16* __restrict__ out)
{
  const int h = blockIdx.y;
  const int q0 = blockIdx.x * 128;
  const int tid = threadIdx.x;
  const int lane = tid & 63;
  const int w = tid >> 6;
  const float slope = slopes[h];

  __shared__ u16 Ks[2][64 * 32];
  __shared__ u16 Vt[64][72];
  __shared__ u16 Pl[4][32][72];

  const u16* qb = q + ((size_t)h * SEQ + q0 + w * 32) * 64;
  bf16x8 qf[2][2];
#pragma unroll
  for (int m = 0; m < 2; ++m)
#pragma unroll
    for (int kk = 0; kk < 2; ++kk)
      qf[m][kk] = *(const bf16x8*)(qb + (m * 16 + (lane & 15)) * 64 + kk * 32 + (lane >> 4) * 8);

  f32x4 o_acc[2][4] = {};
  float mrun[2][4], lrun[2][4];
#pragma unroll
  for (int m = 0; m < 2; ++m)
#pragma unroll
    for (int j = 0; j < 4; ++j) { mrun[m][j] = -1e30f; lrun[m][j] = 0.0f; }

  const int ntiles = (q0 >> 6) + 2;
  const int wmaxrow = q0 + w * 32 + 31;

  const int kkp = w >> 1, halfp = w & 1;
  const u16* gk0 = k + ((size_t)h * SEQ + halfp * 32 + (lane >> 2)) * 64 + kkp * 32 + (lane & 3) * 8;
  u16* lk = &Ks[kkp][(halfp * 32) * 32];
  const u16* gv0 = v + ((size_t)h * SEQ + lane) * 64 + w * 16;

  for (int t = 0; t < ntiles; ++t) {
    const int j0 = t << 6;
    __syncthreads();
    gload_lds16(gk0 + (size_t)j0 * 64, lk);
    gload_lds16(gk0 + (size_t)(j0 + 16) * 64, lk + 16 * 32);
    {
      const u16* gvp = gv0 + (size_t)j0 * 64;
      u16x8 v0 = *(const u16x8*)gvp;
      u16x8 v1 = *(const u16x8*)(gvp + 8);
      const int d0 = w * 16;
#pragma unroll
      for (int i = 0; i < 8; ++i) Vt[d0 + i][lane] = v0[i];
#pragma unroll
      for (int i = 0; i < 8; ++i) Vt[d0 + 8 + i][lane] = v1[i];
    }
    asm volatile("s_waitcnt vmcnt(0)" ::: "memory");
    __syncthreads();

    if (wmaxrow >= j0) {
      f32x4 s[2][4] = {};
#pragma unroll
      for (int kk = 0; kk < 2; ++kk) {
        bf16x8 kf[4];
#pragma unroll
        for (int n = 0; n < 4; ++n)
          kf[n] = *(const bf16x8*)&Ks[kk][(n * 16 + (lane & 15)) * 32 + (lane >> 4) * 8];
#pragma unroll
        for (int m = 0; m < 2; ++m)
#pragma unroll
          for (int n = 0; n < 4; ++n)
            s[m][n] = __builtin_amdgcn_mfma_f32_16x16x32_bf16(qf[m][kk], kf[n], s[m][n], 0, 0, 0);
      }
      const int rq = q0 + w * 32 + ((lane >> 4) << 2);
      const int ck = j0 + (lane & 15);
#pragma unroll
      for (int m = 0; m < 2; ++m) {
#pragma unroll
        for (int j = 0; j < 4; ++j) {
          const int qi = rq + m * 16 + j;
          float mx = -1e30f;
#pragma unroll
          for (int n = 0; n < 4; ++n) {
            const int kj = ck + n * 16;
            float val = s[m][n][j] * 0.125f - slope * (float)(kj - qi);
            val = (kj <= qi) ? val : -1e30f;
            s[m][n][j] = val;
            mx = fmaxf(mx, val);
          }
#pragma unroll
          for (int o = 1; o < 16; o <<= 1) mx = fmaxf(mx, __shfl_xor(mx, o));
          const float mnew = fmaxf(mrun[m][j], mx);
          const float alpha = __expf(mrun[m][j] - mnew);
          mrun[m][j] = mnew;
          float rs = 0.0f;
          const int prow = m * 16 + ((lane >> 4) << 2) + j;
#pragma unroll
          for (int n = 0; n < 4; ++n) {
            const float p = __expf(s[m][n][j] - mnew);
            rs += p;
            Pl[w][prow][n * 16 + (lane & 15)] = f2b(p);
          }
#pragma unroll
          for (int o = 1; o < 16; o <<= 1) rs += __shfl_xor(rs, o);
          lrun[m][j] = lrun[m][j] * alpha + rs;
#pragma unroll
          for (int n = 0; n < 4; ++n) o_acc[m][n][j] *= alpha;
        }
      }
#pragma unroll
      for (int kk = 0; kk < 2; ++kk) {
        bf16x8 pf[2], vf[4];
#pragma unroll
        for (int m = 0; m < 2; ++m)
          pf[m] = *(const bf16x8*)&Pl[w][m * 16 + (lane & 15)][kk * 32 + (lane >> 4) * 8];
#pragma unroll
        for (int n = 0; n < 4; ++n)
          vf[n] = *(const bf16x8*)&Vt[n * 16 + (lane & 15)][kk * 32 + (lane >> 4) * 8];
#pragma unroll
        for (int m = 0; m < 2; ++m)
#pragma unroll
          for (int n = 0; n < 4; ++n)
            o_acc[m][n] = __builtin_amdgcn_mfma_f32_16x16x32_bf16(pf[m], vf[n], o_acc[m][n], 0, 0, 0);
      }
    }
  }

#pragma unroll
  for (int m = 0; m < 2; ++m) {
    const int sbase = q0 + w * 32 + m * 16 + ((lane >> 4) << 2);
#pragma unroll
    for (int n = 0; n < 4; ++n) {
      const int d = h * 64 + n * 16 + (lane & 15);
#pragma unroll
      for (int j = 0; j < 4; ++j)
        out[(size_t)(sbase + j) * 1024 + d] = f2b(o_acc[m][n][j] / lrun[m][j]);
    }
  }
}

// ---------------------------------------------------------------------------
extern "C" void kernel_launch(void* const* d_in, const int* in_sizes, int n_in,
                              void* d_out, int out_size, void* d_ws, size_t ws_size,
                              hipStream_t stream)
{
  (void)in_sizes; (void)n_in; (void)out_size;
  const int* ids = (const int*)d_in[0];
  const float* emb = (const float*)d_in[1];
  const float* slopes = (const float*)d_in[2];
  const float* Wq = (const float*)d_in[3];
  const float* Wk = (const float*)d_in[4];
  const float* Wv = (const float*)d_in[5];
  const float* Wo = (const float*)d_in[6];
  const float* W1 = (const float*)d_in[7];
  const float* b1 = (const float*)d_in[8];
  const float* W2 = (const float*)d_in[9];
  const float* b2 = (const float*)d_in[10];
  const float* g1 = (const float*)d_in[11];
  const float* be1 = (const float*)d_in[12];
  const float* g2 = (const float*)d_in[13];
  const float* be2 = (const float*)d_in[14];
  const float* gf = (const float*)d_in[15];
  const float* bfin = (const float*)d_in[16];

  // scratch carved from d_out (262 MB; all fully rewritten by final GEMM):
  char* ob = (char*)d_out;
  float* x   = (float*)ob;                         // 8 MB fp32 residual
  u16* qb    = (u16*)(ob + (size_t)( 8u << 20));   // 4 MB
  u16* kb    = (u16*)(ob + (size_t)(12u << 20));   // 4 MB
  u16* vb    = (u16*)(ob + (size_t)(16u << 20));   // 4 MB
  u16* attn  = (u16*)(ob + (size_t)(20u << 20));   // 4 MB
  u16* ff    = (u16*)(ob + (size_t)(24u << 20));   // 16 MB
  u16* Wq_b  = (u16*)(ob + (size_t)( 40u << 20));  // 8 MB
  u16* Wk_b  = (u16*)(ob + (size_t)( 48u << 20));  // 8 MB
  u16* Wv_b  = (u16*)(ob + (size_t)( 56u << 20));  // 8 MB
  u16* Wo_b  = (u16*)(ob + (size_t)( 64u << 20));  // 8 MB
  u16* W1_b  = (u16*)(ob + (size_t)( 72u << 20));  // 32 MB
  u16* W2_b  = (u16*)(ob + (size_t)(104u << 20));  // 32 MB
  u16* h     = (u16*)d_ws;                         // 4 MB (read during logits GEMM)
  const size_t emb_b_need = (size_t)(4u << 20) + (size_t)32000 * 1024 * 2;
  const bool emb_fits = ws_size >= emb_b_need;
  u16* emb_b = (u16*)((char*)d_ws + (4u << 20));   // 65.5 MB bf16 emb (if fits)
  float* logits = (float*)d_out;

  // ---- fused weight/emb conversion (one launch) ----
  {
    CvtArgs a;
    const u32 wsz = 4 * 1024 * 1024 / 8;          // per 1024x1024x4-layer tensor
    const u32 fsz = 16 * 1024 * 1024 / 8;
    const u32 esz = 32000 * 1024 / 8;
    a.src[0] = Wq; a.dst[0] = Wq_b;
    a.src[1] = Wk; a.dst[1] = Wk_b;
    a.src[2] = Wv; a.dst[2] = Wv_b;
    a.src[3] = Wo; a.dst[3] = Wo_b;
    a.src[4] = W1; a.dst[4] = W1_b;
    a.src[5] = W2; a.dst[5] = W2_b;
    a.src[6] = emb; a.dst[6] = emb_b;
    a.beg[0] = 0;
    a.beg[1] = wsz;      a.beg[2] = 2 * wsz;  a.beg[3] = 3 * wsz;
    a.beg[4] = 4 * wsz;  a.beg[5] = 4 * wsz + fsz;  a.beg[6] = 4 * wsz + 2 * fsz;
    a.beg[7] = a.beg[6] + esz;
    a.total = emb_fits ? a.beg[7] : a.beg[6];
    cvt_all<<<2048, 256, 0, stream>>>(a);
  }

  gather_kernel<<<2048, 256, 0, stream>>>(ids, emb, x);

  for (int l = 0; l < 4; ++l) {
    const size_t wo = (size_t)l * 1024 * 1024;
    const size_t wf = (size_t)l * 4096 * 1024;
    ln_kernel<<<2048, 256, 0, stream>>>(x, g1 + l * 1024, be1 + l * 1024, h);
    gemm64<1><<<dim3(768, 1, 1), 256, 0, stream>>>(h, Wq_b + wo, Wk_b + wo, Wv_b + wo,
        qb, kb, vb, nullptr, 1024, 1024);
    attn_kernel<<<dim3(16, 16), 256, 0, stream>>>(qb, kb, vb, slopes, attn);
    gemm64<3><<<dim3(256, 1, 2), 256, 0, stream>>>(attn, Wo_b + wo, nullptr, nullptr,
        x, nullptr, nullptr, nullptr, 1024, 1024);
    ln_kernel<<<2048, 256, 0, stream>>>(x, g2 + l * 1024, be2 + l * 1024, h);
    gemm64<2><<<dim3(1024, 1, 1), 256, 0, stream>>>(h, W1_b + wf, nullptr, nullptr,
        ff, nullptr, nullptr, b1 + l * 4096, 4096, 1024);
    gemm64<3><<<dim3(256, 1, 2), 256, 0, stream>>>(ff, W2_b + wf, nullptr, nullptr,
        x, nullptr, nullptr, b2 + l * 1024, 1024, 4096);
  }
  ln_kernel<<<2048, 256, 0, stream>>>(x, gf, bfin, h);
  if (emb_fits) {
    gemm_bt<0, true><<<dim3(4000, 1, 1), 256, 0, stream>>>(h, emb_b, nullptr, nullptr,
        logits, nullptr, nullptr, nullptr, 32000, 1024, 250);
  } else {
    gemm_bt<0, false><<<dim3(4000, 1, 1), 256, 0, stream>>>(h, emb, nullptr, nullptr,
        logits, nullptr, nullptr, nullptr, 32000, 1024, 250);
  }
}

// Round 6
// 1353.376 us; speedup vs baseline: 1.2861x; 1.0561x over previous
//
#include <hip/hip_runtime.h>
#include <hip/hip_bf16.h>

typedef unsigned int u32;
typedef unsigned short u16;
typedef __attribute__((ext_vector_type(8))) __bf16 bf16x8;
typedef __attribute__((ext_vector_type(8))) unsigned short u16x8;
typedef __attribute__((ext_vector_type(4))) float f32x4;

#define SEQ 2048

__device__ __forceinline__ float b2f(u16 u) {
  union { u32 i; float f; } x; x.i = ((u32)u) << 16; return x.f;
}
__device__ __forceinline__ u16 f2b(float f) {
  u32 u = __float_as_uint(f);
  u = (u + 0x7fffu + ((u >> 16) & 1u)) >> 16;
  return (u16)u;
}
__device__ __forceinline__ void gload_lds16(const void* g, void* l) {
  __builtin_amdgcn_global_load_lds((const __attribute__((address_space(1))) u32*)g,
                                   (__attribute__((address_space(3))) u32*)l, 16, 0, 0);
}

// ---------------------------------------------------------------------------
// Fused fp32 -> bf16 bulk convert over up to 7 tensors (one launch).
// ---------------------------------------------------------------------------
struct CvtArgs {
  const float* src[7];
  u16* dst[7];
  u32 beg[8];
  u32 total;
};

__global__ __launch_bounds__(256) void cvt_all(CvtArgs a)
{
  for (u32 i = blockIdx.x * 256 + threadIdx.x; i < a.total; i += gridDim.x * 256) {
    int s = 0;
#pragma unroll
    for (int k = 1; k < 7; ++k) s += (i >= a.beg[k]);
    const u32 li = i - a.beg[s];
    const float* in = a.src[s];
    const float4 f0 = ((const float4*)in)[(size_t)li * 2];
    const float4 f1 = ((const float4*)in)[(size_t)li * 2 + 1];
    union { bf16x8 b; u16x8 u; } r;
    r.b[0] = (__bf16)f0.x; r.b[1] = (__bf16)f0.y;
    r.b[2] = (__bf16)f0.z; r.b[3] = (__bf16)f0.w;
    r.b[4] = (__bf16)f1.x; r.b[5] = (__bf16)f1.y;
    r.b[6] = (__bf16)f1.z; r.b[7] = (__bf16)f1.w;
    *(u16x8*)(a.dst[s] + (size_t)li * 8) = r.u;
  }
}

// ---------------------------------------------------------------------------
// 128x128 / BK=64 GEMM (all-bf16). LDS layout XOR-swizzled (g ^= row&7):
// linear gload_lds dest + pre-swizzled global SOURCE + same XOR on ds_read.
// 2-barrier loop (R2-proven ordering), half the barriers of BK=32.
// EPI 0: fp32 store (logits)
// ---------------------------------------------------------------------------
template <int EPI>
__global__ __launch_bounds__(256) void gemm_bt64(
    const u16* __restrict__ A, const u16* __restrict__ Bt,
    void* __restrict__ C0, int N, int K)
{
  __shared__ u16 As[128 * 64];
  __shared__ u16 Bs[128 * 64];
  const int tid = threadIdx.x;
  const int lane = tid & 63;
  const int w = tid >> 6;
  const int wr = w >> 1;
  const int wc = w & 1;

  const int T = (int)gridDim.x;
  const int bid = (int)blockIdx.x;
  const int q8 = T >> 3, r8 = T & 7;
  const int xcd = bid & 7, base = bid >> 3;
  int swz = (xcd < r8 ? xcd * (q8 + 1) : r8 * (q8 + 1) + (xcd - r8) * q8) + base;
  const int m0 = (swz & 15) * 128;
  const int n0 = (swz >> 4) * 128;

  f32x4 acc[4][4] = {};

  // staging: per wave 4 calls x 1024B; lane l -> row_local l>>3, granule l&7;
  // source granule pre-swizzled: gs = (l&7) ^ (l>>3)  (row&7 == l>>3)
  const int rs = lane >> 3;
  const int gs = (lane & 7) ^ rs;
  const u16* ga0 = A + (size_t)(m0 + w * 32 + rs) * K + gs * 8;
  const u16* gb0 = Bt + (size_t)(n0 + w * 32 + rs) * K + gs * 8;
  u16* la = &As[(w * 32) * 64];
  u16* lb = &Bs[(w * 32) * 64];

  // ds_read offsets (u16 units), loop-invariant:
  // row = q*64 + m*16 + (lane&15); col = ((ks*4 + (lane>>4)) ^ (lane&7)) * 8
  const int xg = lane & 7;
  int coff[2];
#pragma unroll
  for (int ks = 0; ks < 2; ++ks)
    coff[ks] = ((ks * 4 + (lane >> 4)) ^ xg) * 8;
  const int ra = (wr * 64 + (lane & 15)) * 64;
  const int rb = (wc * 64 + (lane & 15)) * 64;

  for (int kt = 0; kt < K; kt += 64) {
    __syncthreads();
#pragma unroll
    for (int c = 0; c < 4; ++c) {
      gload_lds16(ga0 + (size_t)c * 8 * K + kt, la + c * 8 * 64);
      gload_lds16(gb0 + (size_t)c * 8 * K + kt, lb + c * 8 * 64);
    }
    asm volatile("s_waitcnt vmcnt(0)" ::: "memory");
    __syncthreads();
#pragma unroll
    for (int ks = 0; ks < 2; ++ks) {
      bf16x8 af[4], bfr[4];
#pragma unroll
      for (int m = 0; m < 4; ++m)
        af[m] = *(const bf16x8*)&As[ra + m * 16 * 64 + coff[ks]];
#pragma unroll
      for (int n = 0; n < 4; ++n)
        bfr[n] = *(const bf16x8*)&Bs[rb + n * 16 * 64 + coff[ks]];
#pragma unroll
      for (int m = 0; m < 4; ++m)
#pragma unroll
        for (int n = 0; n < 4; ++n)
          acc[m][n] = __builtin_amdgcn_mfma_f32_16x16x32_bf16(af[m], bfr[n], acc[m][n], 0, 0, 0);
    }
  }

#pragma unroll
  for (int m = 0; m < 4; ++m) {
    const int rowb = m0 + wr * 64 + m * 16 + ((lane >> 4) << 2);
#pragma unroll
    for (int n = 0; n < 4; ++n) {
      const int col = n0 + wc * 64 + n * 16 + (lane & 15);
#pragma unroll
      for (int j = 0; j < 4; ++j)
        ((float*)C0)[(size_t)(rowb + j) * N + col] = acc[m][n][j];
    }
  }
}

// ---------------------------------------------------------------------------
// 64x128 / BK=64 GEMM for layer GEMMs. Same swizzle scheme as gemm_bt64.
// EPI 1: QKV head-major bf16 (which = swz>>8, needs T=768)
// EPI 2: bf16 gelu(acc + bias)
// EPI 3: atomicAdd fp32 (+bias on z==0), split-K via gridDim.z
// ---------------------------------------------------------------------------
template <int EPI>
__global__ __launch_bounds__(256) void gemm64(
    const u16* __restrict__ A, const u16* __restrict__ B0,
    const u16* __restrict__ B1, const u16* __restrict__ B2,
    void* __restrict__ C0, void* __restrict__ C1, void* __restrict__ C2,
    const float* __restrict__ bias, int N, int K)
{
  __shared__ u16 As[64 * 64];
  __shared__ u16 Bs[128 * 64];
  const int tid = threadIdx.x;
  const int lane = tid & 63;
  const int w = tid >> 6;
  const int wr = w >> 1;
  const int wc = w & 1;

  const int T = (int)gridDim.x;
  const int bid = (int)blockIdx.x;
  const int q8 = T >> 3, r8 = T & 7;
  const int xcd = bid & 7, base = bid >> 3;
  int swz = (xcd < r8 ? xcd * (q8 + 1) : r8 * (q8 + 1) + (xcd - r8) * q8) + base;
  int which = 0;
  if (EPI == 1) which = swz >> 8;
  const u16* Bt = (which == 0) ? B0 : (which == 1) ? B1 : B2;
  const int m0 = (swz & 31) * 64;
  const int n0 = (EPI == 1 ? ((swz >> 5) & 7) : (swz >> 5)) * 128;

  const int kchunk = K / (int)gridDim.z;
  const int kbeg = (int)blockIdx.z * kchunk;
  const int kend = kbeg + kchunk;

  f32x4 acc[2][4] = {};

  const int rs = lane >> 3;
  const int gs = (lane & 7) ^ rs;
  const u16* ga0 = A + (size_t)(m0 + w * 16 + rs) * K + gs * 8;
  const u16* gb0 = Bt + (size_t)(n0 + w * 32 + rs) * K + gs * 8;
  u16* la = &As[(w * 16) * 64];
  u16* lb = &Bs[(w * 32) * 64];

  const int xg = lane & 7;
  int coff[2];
#pragma unroll
  for (int ks = 0; ks < 2; ++ks)
    coff[ks] = ((ks * 4 + (lane >> 4)) ^ xg) * 8;
  const int ra = (wr * 32 + (lane & 15)) * 64;
  const int rb = (wc * 64 + (lane & 15)) * 64;

  for (int kt = kbeg; kt < kend; kt += 64) {
    __syncthreads();
#pragma unroll
    for (int c = 0; c < 2; ++c)
      gload_lds16(ga0 + (size_t)c * 8 * K + kt, la + c * 8 * 64);
#pragma unroll
    for (int c = 0; c < 4; ++c)
      gload_lds16(gb0 + (size_t)c * 8 * K + kt, lb + c * 8 * 64);
    asm volatile("s_waitcnt vmcnt(0)" ::: "memory");
    __syncthreads();
#pragma unroll
    for (int ks = 0; ks < 2; ++ks) {
      bf16x8 af[2], bfr[4];
#pragma unroll
      for (int m = 0; m < 2; ++m)
        af[m] = *(const bf16x8*)&As[ra + m * 16 * 64 + coff[ks]];
#pragma unroll
      for (int n = 0; n < 4; ++n)
        bfr[n] = *(const bf16x8*)&Bs[rb + n * 16 * 64 + coff[ks]];
#pragma unroll
      for (int m = 0; m < 2; ++m)
#pragma unroll
        for (int n = 0; n < 4; ++n)
          acc[m][n] = __builtin_amdgcn_mfma_f32_16x16x32_bf16(af[m], bfr[n], acc[m][n], 0, 0, 0);
    }
  }

#pragma unroll
  for (int m = 0; m < 2; ++m) {
    const int rowb = m0 + wr * 32 + m * 16 + ((lane >> 4) << 2);
#pragma unroll
    for (int n = 0; n < 4; ++n) {
      const int col = n0 + wc * 64 + n * 16 + (lane & 15);
#pragma unroll
      for (int j = 0; j < 4; ++j) {
        const int r = rowb + j;
        float v = acc[m][n][j];
        if (EPI == 1) {
          u16* outp = (u16*)((which == 0) ? C0 : (which == 1) ? C1 : C2);
          outp[((size_t)(col >> 6) * SEQ + r) * 64 + (col & 63)] = f2b(v);
        } else if (EPI == 2) {
          float xx = v + bias[col];
          float ge = 0.5f * xx * (1.0f + erff(xx * 0.70710678118654752f));
          ((u16*)C0)[(size_t)r * N + col] = f2b(ge);
        } else {
          float xx = v;
          if (bias != nullptr && blockIdx.z == 0) xx += bias[col];
          atomicAdd(&((float*)C0)[(size_t)r * N + col], xx);
        }
      }
    }
  }
}

// ---------------------------------------------------------------------------
// Fallback logits GEMM (fp32 B, BK=32, R2-proven) if emb_bf16 doesn't fit ws.
// ---------------------------------------------------------------------------
__global__ __launch_bounds__(256) void gemm_f32b(
    const u16* __restrict__ A, const float* __restrict__ Bt,
    float* __restrict__ C0, int N, int K)
{
  __shared__ u16 As[128 * 32];
  __shared__ u16 Bs[128 * 32];
  const int tid = threadIdx.x;
  const int lane = tid & 63;
  const int w = tid >> 6;
  const int wr = w >> 1;
  const int wc = w & 1;

  const int T = (int)gridDim.x;
  const int bid = (int)blockIdx.x;
  const int q8 = T >> 3, r8 = T & 7;
  const int xcd = bid & 7, base = bid >> 3;
  int swz = (xcd < r8 ? xcd * (q8 + 1) : r8 * (q8 + 1) + (xcd - r8) * q8) + base;
  const int m0 = (swz & 15) * 128;
  const int n0 = (swz >> 4) * 128;

  f32x4 acc[4][4] = {};
  const u16* ga0 = A + (size_t)(m0 + w * 32 + (lane >> 2)) * K + (lane & 3) * 8;
  u16* la = &As[(w * 32) * 32];
  const float* gb32 = Bt + (size_t)(n0 + (tid >> 1)) * K + (tid & 1) * 16;
  u16* lbw = &Bs[(tid >> 1) * 32 + (tid & 1) * 16];

  for (int kt = 0; kt < K; kt += 32) {
    __syncthreads();
    gload_lds16(ga0 + kt, la);
    gload_lds16(ga0 + kt + 16 * K, la + 16 * 32);
    {
      const float4 f0 = *(const float4*)(gb32 + kt);
      const float4 f1 = *(const float4*)(gb32 + kt + 4);
      const float4 f2 = *(const float4*)(gb32 + kt + 8);
      const float4 f3 = *(const float4*)(gb32 + kt + 12);
      union { bf16x8 b; u16x8 u; } lo, hi;
      lo.b[0] = (__bf16)f0.x; lo.b[1] = (__bf16)f0.y;
      lo.b[2] = (__bf16)f0.z; lo.b[3] = (__bf16)f0.w;
      lo.b[4] = (__bf16)f1.x; lo.b[5] = (__bf16)f1.y;
      lo.b[6] = (__bf16)f1.z; lo.b[7] = (__bf16)f1.w;
      hi.b[0] = (__bf16)f2.x; hi.b[1] = (__bf16)f2.y;
      hi.b[2] = (__bf16)f2.z; hi.b[3] = (__bf16)f2.w;
      hi.b[4] = (__bf16)f3.x; hi.b[5] = (__bf16)f3.y;
      hi.b[6] = (__bf16)f3.z; hi.b[7] = (__bf16)f3.w;
      *(u16x8*)lbw = lo.u;
      *(u16x8*)(lbw + 8) = hi.u;
    }
    asm volatile("s_waitcnt vmcnt(0)" ::: "memory");
    __syncthreads();
    bf16x8 af[4], bfr[4];
#pragma unroll
    for (int m = 0; m < 4; ++m)
      af[m] = *(const bf16x8*)&As[(wr * 64 + m * 16 + (lane & 15)) * 32 + (lane >> 4) * 8];
#pragma unroll
    for (int n = 0; n < 4; ++n)
      bfr[n] = *(const bf16x8*)&Bs[(wc * 64 + n * 16 + (lane & 15)) * 32 + (lane >> 4) * 8];
#pragma unroll
    for (int m = 0; m < 4; ++m)
#pragma unroll
      for (int n = 0; n < 4; ++n)
        acc[m][n] = __builtin_amdgcn_mfma_f32_16x16x32_bf16(af[m], bfr[n], acc[m][n], 0, 0, 0);
  }

#pragma unroll
  for (int m = 0; m < 4; ++m) {
    const int rowb = m0 + wr * 64 + m * 16 + ((lane >> 4) << 2);
#pragma unroll
    for (int n = 0; n < 4; ++n) {
      const int col = n0 + wc * 64 + n * 16 + (lane & 15);
#pragma unroll
      for (int j = 0; j < 4; ++j)
        C0[(size_t)(rowb + j) * N + col] = acc[m][n][j];
    }
  }
}

// ---------------------------------------------------------------------------
// LayerNorm: fp32 x[row][1024] -> bf16 out; g/b fp32
// ---------------------------------------------------------------------------
__global__ __launch_bounds__(256) void ln_kernel(const float* __restrict__ x,
    const float* __restrict__ g, const float* __restrict__ b, u16* __restrict__ out)
{
  const int row = blockIdx.x;
  const int tid = threadIdx.x;
  const float4 v = ((const float4*)(x + (size_t)row * 1024))[tid];
  float s = v.x + v.y + v.z + v.w;
  float sq = v.x * v.x + v.y * v.y + v.z * v.z + v.w * v.w;
#pragma unroll
  for (int o = 1; o < 64; o <<= 1) { s += __shfl_xor(s, o); sq += __shfl_xor(sq, o); }
  __shared__ float ss[4], ssq[4];
  if ((tid & 63) == 0) { ss[tid >> 6] = s; ssq[tid >> 6] = sq; }
  __syncthreads();
  s = ss[0] + ss[1] + ss[2] + ss[3];
  sq = ssq[0] + ssq[1] + ssq[2] + ssq[3];
  const float mean = s * (1.0f / 1024.0f);
  const float var = sq * (1.0f / 1024.0f) - mean * mean;
  const float rstd = rsqrtf(var + 1e-5f);
  const int c = tid * 4;
  u16* o4 = out + (size_t)row * 1024 + c;
  const float4 gg = ((const float4*)g)[tid];
  const float4 bb = ((const float4*)b)[tid];
  o4[0] = f2b((v.x - mean) * rstd * gg.x + bb.x);
  o4[1] = f2b((v.y - mean) * rstd * gg.y + bb.y);
  o4[2] = f2b((v.z - mean) * rstd * gg.z + bb.z);
  o4[3] = f2b((v.w - mean) * rstd * gg.w + bb.w);
}

// ---------------------------------------------------------------------------
// Embedding gather: x[s][d] = emb_fp32[ids[s]][d]
// ---------------------------------------------------------------------------
__global__ __launch_bounds__(256) void gather_kernel(const int* __restrict__ ids,
    const float* __restrict__ emb, float* __restrict__ x)
{
  const int srow = blockIdx.x;
  const int tid = threadIdx.x;
  const int id = ids[srow];
  ((float4*)(x + (size_t)srow * 1024))[tid] =
      ((const float4*)(emb + (size_t)id * 1024))[tid];
}

// ---------------------------------------------------------------------------
// Flash attention w/ ALiBi + causal. 1-D grid (256): head-major per XCD so
// same-head blocks (sharing 512KB K/V) co-locate on one XCD's L2.
// One block = (head, 128 q rows), 4 waves x 32 rows, KV tiles of 64.
// ---------------------------------------------------------------------------
__global__ __launch_bounds__(256) void attn_kernel(
    const u16* __restrict__ q, const u16* __restrict__ k, const u16* __restrict__ v,
    const float* __restrict__ slopes, u16* __restrict__ out)
{
  const int bid = (int)blockIdx.x;
  const int swz = (bid & 7) * 32 + (bid >> 3);   // T=256: q8=32, r8=0
  const int h = swz >> 4;
  const int q0 = (swz & 15) * 128;
  const int tid = threadIdx.x;
  const int lane = tid & 63;
  const int w = tid >> 6;
  const float slope = slopes[h];

  __shared__ u16 Ks[2][64 * 32];
  __shared__ u16 Vt[64][72];
  __shared__ u16 Pl[4][32][72];

  const u16* qb = q + ((size_t)h * SEQ + q0 + w * 32) * 64;
  bf16x8 qf[2][2];
#pragma unroll
  for (int m = 0; m < 2; ++m)
#pragma unroll
    for (int kk = 0; kk < 2; ++kk)
      qf[m][kk] = *(const bf16x8*)(qb + (m * 16 + (lane & 15)) * 64 + kk * 32 + (lane >> 4) * 8);

  f32x4 o_acc[2][4] = {};
  float mrun[2][4], lrun[2][4];
#pragma unroll
  for (int m = 0; m < 2; ++m)
#pragma unroll
    for (int j = 0; j < 4; ++j) { mrun[m][j] = -1e30f; lrun[m][j] = 0.0f; }

  const int ntiles = (q0 >> 6) + 2;
  const int wmaxrow = q0 + w * 32 + 31;

  const int kkp = w >> 1, halfp = w & 1;
  const u16* gk0 = k + ((size_t)h * SEQ + halfp * 32 + (lane >> 2)) * 64 + kkp * 32 + (lane & 3) * 8;
  u16* lk = &Ks[kkp][(halfp * 32) * 32];
  const u16* gv0 = v + ((size_t)h * SEQ + lane) * 64 + w * 16;

  for (int t = 0; t < ntiles; ++t) {
    const int j0 = t << 6;
    __syncthreads();
    gload_lds16(gk0 + (size_t)j0 * 64, lk);
    gload_lds16(gk0 + (size_t)(j0 + 16) * 64, lk + 16 * 32);
    {
      const u16* gvp = gv0 + (size_t)j0 * 64;
      u16x8 v0 = *(const u16x8*)gvp;
      u16x8 v1 = *(const u16x8*)(gvp + 8);
      const int d0 = w * 16;
#pragma unroll
      for (int i = 0; i < 8; ++i) Vt[d0 + i][lane] = v0[i];
#pragma unroll
      for (int i = 0; i < 8; ++i) Vt[d0 + 8 + i][lane] = v1[i];
    }
    asm volatile("s_waitcnt vmcnt(0)" ::: "memory");
    __syncthreads();

    if (wmaxrow >= j0) {
      f32x4 s[2][4] = {};
      __builtin_amdgcn_s_setprio(1);
#pragma unroll
      for (int kk = 0; kk < 2; ++kk) {
        bf16x8 kf[4];
#pragma unroll
        for (int n = 0; n < 4; ++n)
          kf[n] = *(const bf16x8*)&Ks[kk][(n * 16 + (lane & 15)) * 32 + (lane >> 4) * 8];
#pragma unroll
        for (int m = 0; m < 2; ++m)
#pragma unroll
          for (int n = 0; n < 4; ++n)
            s[m][n] = __builtin_amdgcn_mfma_f32_16x16x32_bf16(qf[m][kk], kf[n], s[m][n], 0, 0, 0);
      }
      __builtin_amdgcn_s_setprio(0);
      const int rq = q0 + w * 32 + ((lane >> 4) << 2);
      const int ck = j0 + (lane & 15);
#pragma unroll
      for (int m = 0; m < 2; ++m) {
#pragma unroll
        for (int j = 0; j < 4; ++j) {
          const int qi = rq + m * 16 + j;
          float mx = -1e30f;
#pragma unroll
          for (int n = 0; n < 4; ++n) {
            const int kj = ck + n * 16;
            float val = s[m][n][j] * 0.125f - slope * (float)(kj - qi);
            val = (kj <= qi) ? val : -1e30f;
            s[m][n][j] = val;
            mx = fmaxf(mx, val);
          }
#pragma unroll
          for (int o = 1; o < 16; o <<= 1) mx = fmaxf(mx, __shfl_xor(mx, o));
          const float mnew = fmaxf(mrun[m][j], mx);
          const float alpha = __expf(mrun[m][j] - mnew);
          mrun[m][j] = mnew;
          float rs = 0.0f;
          const int prow = m * 16 + ((lane >> 4) << 2) + j;
#pragma unroll
          for (int n = 0; n < 4; ++n) {
            const float p = __expf(s[m][n][j] - mnew);
            rs += p;
            Pl[w][prow][n * 16 + (lane & 15)] = f2b(p);
          }
#pragma unroll
          for (int o = 1; o < 16; o <<= 1) rs += __shfl_xor(rs, o);
          lrun[m][j] = lrun[m][j] * alpha + rs;
#pragma unroll
          for (int n = 0; n < 4; ++n) o_acc[m][n][j] *= alpha;
        }
      }
      __builtin_amdgcn_s_setprio(1);
#pragma unroll
      for (int kk = 0; kk < 2; ++kk) {
        bf16x8 pf[2], vf[4];
#pragma unroll
        for (int m = 0; m < 2; ++m)
          pf[m] = *(const bf16x8*)&Pl[w][m * 16 + (lane & 15)][kk * 32 + (lane >> 4) * 8];
#pragma unroll
        for (int n = 0; n < 4; ++n)
          vf[n] = *(const bf16x8*)&Vt[n * 16 + (lane & 15)][kk * 32 + (lane >> 4) * 8];
#pragma unroll
        for (int m = 0; m < 2; ++m)
#pragma unroll
          for (int n = 0; n < 4; ++n)
            o_acc[m][n] = __builtin_amdgcn_mfma_f32_16x16x32_bf16(pf[m], vf[n], o_acc[m][n], 0, 0, 0);
      }
      __builtin_amdgcn_s_setprio(0);
    }
  }

#pragma unroll
  for (int m = 0; m < 2; ++m) {
    const int sbase = q0 + w * 32 + m * 16 + ((lane >> 4) << 2);
#pragma unroll
    for (int n = 0; n < 4; ++n) {
      const int d = h * 64 + n * 16 + (lane & 15);
#pragma unroll
      for (int j = 0; j < 4; ++j)
        out[(size_t)(sbase + j) * 1024 + d] = f2b(o_acc[m][n][j] / lrun[m][j]);
    }
  }
}

// ---------------------------------------------------------------------------
extern "C" void kernel_launch(void* const* d_in, const int* in_sizes, int n_in,
                              void* d_out, int out_size, void* d_ws, size_t ws_size,
                              hipStream_t stream)
{
  (void)in_sizes; (void)n_in; (void)out_size;
  const int* ids = (const int*)d_in[0];
  const float* emb = (const float*)d_in[1];
  const float* slopes = (const float*)d_in[2];
  const float* Wq = (const float*)d_in[3];
  const float* Wk = (const float*)d_in[4];
  const float* Wv = (const float*)d_in[5];
  const float* Wo = (const float*)d_in[6];
  const float* W1 = (const float*)d_in[7];
  const float* b1 = (const float*)d_in[8];
  const float* W2 = (const float*)d_in[9];
  const float* b2 = (const float*)d_in[10];
  const float* g1 = (const float*)d_in[11];
  const float* be1 = (const float*)d_in[12];
  const float* g2 = (const float*)d_in[13];
  const float* be2 = (const float*)d_in[14];
  const float* gf = (const float*)d_in[15];
  const float* bfin = (const float*)d_in[16];

  char* ob = (char*)d_out;
  float* x   = (float*)ob;                         // 8 MB fp32 residual
  u16* qb    = (u16*)(ob + (size_t)( 8u << 20));   // 4 MB
  u16* kb    = (u16*)(ob + (size_t)(12u << 20));   // 4 MB
  u16* vb    = (u16*)(ob + (size_t)(16u << 20));   // 4 MB
  u16* attn  = (u16*)(ob + (size_t)(20u << 20));   // 4 MB
  u16* ff    = (u16*)(ob + (size_t)(24u << 20));   // 16 MB
  u16* Wq_b  = (u16*)(ob + (size_t)( 40u << 20));  // 8 MB
  u16* Wk_b  = (u16*)(ob + (size_t)( 48u << 20));  // 8 MB
  u16* Wv_b  = (u16*)(ob + (size_t)( 56u << 20));  // 8 MB
  u16* Wo_b  = (u16*)(ob + (size_t)( 64u << 20));  // 8 MB
  u16* W1_b  = (u16*)(ob + (size_t)( 72u << 20));  // 32 MB
  u16* W2_b  = (u16*)(ob + (size_t)(104u << 20));  // 32 MB
  u16* h     = (u16*)d_ws;                         // 4 MB
  const size_t emb_b_need = (size_t)(4u << 20) + (size_t)32000 * 1024 * 2;
  const bool emb_fits = ws_size >= emb_b_need;
  u16* emb_b = (u16*)((char*)d_ws + (4u << 20));
  float* logits = (float*)d_out;

  {
    CvtArgs a;
    const u32 wsz = 4 * 1024 * 1024 / 8;
    const u32 fsz = 16 * 1024 * 1024 / 8;
    const u32 esz = 32000 * 1024 / 8;
    a.src[0] = Wq; a.dst[0] = Wq_b;
    a.src[1] = Wk; a.dst[1] = Wk_b;
    a.src[2] = Wv; a.dst[2] = Wv_b;
    a.src[3] = Wo; a.dst[3] = Wo_b;
    a.src[4] = W1; a.dst[4] = W1_b;
    a.src[5] = W2; a.dst[5] = W2_b;
    a.src[6] = emb; a.dst[6] = emb_b;
    a.beg[0] = 0;
    a.beg[1] = wsz;      a.beg[2] = 2 * wsz;  a.beg[3] = 3 * wsz;
    a.beg[4] = 4 * wsz;  a.beg[5] = 4 * wsz + fsz;  a.beg[6] = 4 * wsz + 2 * fsz;
    a.beg[7] = a.beg[6] + esz;
    a.total = emb_fits ? a.beg[7] : a.beg[6];
    cvt_all<<<2048, 256, 0, stream>>>(a);
  }

  gather_kernel<<<2048, 256, 0, stream>>>(ids, emb, x);

  for (int l = 0; l < 4; ++l) {
    const size_t wo = (size_t)l * 1024 * 1024;
    const size_t wf = (size_t)l * 4096 * 1024;
    ln_kernel<<<2048, 256, 0, stream>>>(x, g1 + l * 1024, be1 + l * 1024, h);
    gemm64<1><<<dim3(768, 1, 1), 256, 0, stream>>>(h, Wq_b + wo, Wk_b + wo, Wv_b + wo,
        qb, kb, vb, nullptr, 1024, 1024);
    attn_kernel<<<dim3(256, 1, 1), 256, 0, stream>>>(qb, kb, vb, slopes, attn);
    gemm64<3><<<dim3(256, 1, 2), 256, 0, stream>>>(attn, Wo_b + wo, nullptr, nullptr,
        x, nullptr, nullptr, nullptr, 1024, 1024);
    ln_kernel<<<2048, 256, 0, stream>>>(x, g2 + l * 1024, be2 + l * 1024, h);
    gemm64<2><<<dim3(1024, 1, 1), 256, 0, stream>>>(h, W1_b + wf, nullptr, nullptr,
        ff, nullptr, nullptr, b1 + l * 4096, 4096, 1024);
    gemm64<3><<<dim3(256, 1, 2), 256, 0, stream>>>(ff, W2_b + wf, nullptr, nullptr,
        x, nullptr, nullptr, b2 + l * 1024, 1024, 4096);
  }
  ln_kernel<<<2048, 256, 0, stream>>>(x, gf, bfin, h);
  if (emb_fits) {
    gemm_bt64<0><<<dim3(4000, 1, 1), 256, 0, stream>>>(h, emb_b, logits, 32000, 1024);
  } else {
    gemm_f32b<<<dim3(4000, 1, 1), 256, 0, stream>>>(h, emb, logits, 32000, 1024);
  }
}